// Round 1
// baseline (711.444 us; speedup 1.0000x reference)
//
#include <hip/hip_runtime.h>
#include <math.h>

#define N_NODES 50000
#define EDGES   800000
#define ETOT    (EDGES + N_NODES)
#define HID     128
#define NH      4

// ---------------------------------------------------------------------------
// CSR build: counts -> exclusive scan -> scatter (dst-grouped src lists)
// ---------------------------------------------------------------------------
__global__ void count_kernel(const int* __restrict__ ei, int* __restrict__ counts) {
    int i = blockIdx.x * blockDim.x + threadIdx.x;
    if (i >= ETOT) return;
    int d = (i < EDGES) ? ei[EDGES + i] : (i - EDGES);
    atomicAdd(&counts[d], 1);
}

#define SCAN_T 1024
__global__ __launch_bounds__(SCAN_T) void scan_kernel(const int* __restrict__ counts,
                                                      int* __restrict__ offsets,
                                                      int* __restrict__ cursor, int n) {
    __shared__ int part[SCAN_T];
    int t = threadIdx.x;
    int chunk = (n + SCAN_T - 1) / SCAN_T;
    int lo = t * chunk;
    int hi = lo + chunk; if (hi > n) hi = n;
    int sum = 0;
    for (int i = lo; i < hi; i++) sum += counts[i];
    part[t] = sum;
    __syncthreads();
    for (int off = 1; off < SCAN_T; off <<= 1) {
        int v = part[t];
        int add = (t >= off) ? part[t - off] : 0;
        __syncthreads();
        part[t] = v + add;
        __syncthreads();
    }
    int run = part[t] - sum;  // exclusive
    for (int i = lo; i < hi; i++) { offsets[i] = run; cursor[i] = run; run += counts[i]; }
    if (t == SCAN_T - 1) offsets[n] = run;
}

__global__ void scatter_kernel(const int* __restrict__ ei, int* __restrict__ cursor,
                               int* __restrict__ csr) {
    int i = blockIdx.x * blockDim.x + threadIdx.x;
    if (i >= ETOT) return;
    int s, d;
    if (i < EDGES) { s = ei[i]; d = ei[EDGES + i]; }
    else           { s = d = i - EDGES; }
    int pos = atomicAdd(&cursor[d], 1);
    csr[pos] = s;
}

// ---------------------------------------------------------------------------
// Fold bias + BN(eval) into per-channel affine: out = relu(acc*A + B)
//   v = acc + bias; bn = (v-mean)*gamma*rsqrt(var+eps)+beta = acc*A + B
// coef layout: [A1(128) | B1(128) | A2(128) | B2(128)]
// ---------------------------------------------------------------------------
__global__ void coef_kernel(const float* __restrict__ b1, const float* __restrict__ g1,
                            const float* __restrict__ be1, const float* __restrict__ mn1,
                            const float* __restrict__ vr1,
                            const float* __restrict__ b2, const float* __restrict__ g2,
                            const float* __restrict__ be2, const float* __restrict__ mn2,
                            const float* __restrict__ vr2, float* __restrict__ coef) {
    int t = threadIdx.x;
    if (t < 128) {
        float sc = g1[t] * rsqrtf(vr1[t] + 1e-5f);
        coef[t]       = sc;
        coef[128 + t] = be1[t] + (b1[t] - mn1[t]) * sc;
    } else {
        int c = t - 128;
        float sc = g2[c] * rsqrtf(vr2[c] + 1e-5f);
        coef[256 + c] = sc;
        coef[384 + c] = be2[c] + (b2[c] - mn2[c]) * sc;
    }
}

// ---------------------------------------------------------------------------
// GEMM: Hout[N][128] = X[N][K] @ W[K][128], fp32.
// Block: 256 threads, 64 rows per block. LDS: W chunk 64x128, X chunk 64x64(+1 pad).
// Thread: 2 rows (rowg=t&31) x 16 cols (colg=t>>5), 32 accumulators.
// ---------------------------------------------------------------------------
#define GR 64
#define KC 64
__global__ __launch_bounds__(256) void gemm_kernel(const float* __restrict__ X,
                                                   const float* __restrict__ W,
                                                   float* __restrict__ Hout,
                                                   int Nrows, int K) {
    __shared__ float Ws[KC][128];
    __shared__ float Xs[GR][KC + 1];
    int t = threadIdx.x;
    int rowBase = blockIdx.x * GR;
    int rowg = t & 31;
    int colg = t >> 5;

    float acc0[16], acc1[16];
#pragma unroll
    for (int j = 0; j < 16; j++) { acc0[j] = 0.f; acc1[j] = 0.f; }

    for (int k0 = 0; k0 < K; k0 += KC) {
        // stage X chunk (64 rows x 64 k)
        for (int s = t; s < GR * (KC / 4); s += 256) {
            int row = s >> 4;
            int kq  = s & 15;
            int gr  = rowBase + row;
            float4 v = make_float4(0.f, 0.f, 0.f, 0.f);
            if (gr < Nrows) v = *(const float4*)&X[(size_t)gr * K + k0 + kq * 4];
            Xs[row][kq * 4 + 0] = v.x; Xs[row][kq * 4 + 1] = v.y;
            Xs[row][kq * 4 + 2] = v.z; Xs[row][kq * 4 + 3] = v.w;
        }
        // stage W chunk (64 k x 128 cols)
        for (int s = t; s < KC * 32; s += 256) {
            int kr = s >> 5;
            int cq = s & 31;
            *(float4*)&Ws[kr][cq * 4] = *(const float4*)&W[(size_t)(k0 + kr) * 128 + cq * 4];
        }
        __syncthreads();
#pragma unroll 8
        for (int kk = 0; kk < KC; kk++) {
            float x0 = Xs[2 * rowg][kk];
            float x1 = Xs[2 * rowg + 1][kk];
            const float* wr = &Ws[kk][colg * 16];
            float wv[16];
            *(float4*)&wv[0]  = *(const float4*)(wr);
            *(float4*)&wv[4]  = *(const float4*)(wr + 4);
            *(float4*)&wv[8]  = *(const float4*)(wr + 8);
            *(float4*)&wv[12] = *(const float4*)(wr + 12);
#pragma unroll
            for (int j = 0; j < 16; j++) {
                acc0[j] += x0 * wv[j];
                acc1[j] += x1 * wv[j];
            }
        }
        __syncthreads();
    }
    int r0 = rowBase + 2 * rowg;
    int r1 = r0 + 1;
    if (r0 < Nrows) {
#pragma unroll
        for (int j = 0; j < 4; j++)
            *(float4*)&Hout[(size_t)r0 * 128 + colg * 16 + j * 4] = *(float4*)&acc0[j * 4];
    }
    if (r1 < Nrows) {
#pragma unroll
        for (int j = 0; j < 4; j++)
            *(float4*)&Hout[(size_t)r1 * 128 + colg * 16 + j * 4] = *(float4*)&acc1[j * 4];
    }
}

// ---------------------------------------------------------------------------
// Per-node attention dots: a_s[n,h] = sum_c h[n,h,c]*att_src[h,c]; same a_d.
// One thread per (node, head).
// ---------------------------------------------------------------------------
__global__ void attdot_kernel(const float* __restrict__ hfeat,
                              const float* __restrict__ att_src,
                              const float* __restrict__ att_dst,
                              float* __restrict__ a_s, float* __restrict__ a_d) {
    int idx = blockIdx.x * blockDim.x + threadIdx.x;
    if (idx >= N_NODES * NH) return;
    int n = idx >> 2, hd = idx & 3;
    const float4* hp = (const float4*)(hfeat + (size_t)n * HID + hd * 32);
    const float4* sp = (const float4*)(att_src + hd * 32);
    const float4* dp = (const float4*)(att_dst + hd * 32);
    float ss = 0.f, dd = 0.f;
#pragma unroll
    for (int i = 0; i < 8; i++) {
        float4 hv = hp[i], sv = sp[i], dv = dp[i];
        ss += hv.x * sv.x + hv.y * sv.y + hv.z * sv.z + hv.w * sv.w;
        dd += hv.x * dv.x + hv.y * dv.y + hv.z * dv.z + hv.w * dv.w;
    }
    a_s[idx] = ss;
    a_d[idx] = dd;
}

// ---------------------------------------------------------------------------
// Gather/softmax/aggregate: one wave per dst node, atomic-free.
// Phase 1: per-head max over incoming edges (lane-strided + butterfly).
// Phase 2: per-head exp-sum (lane-strided + butterfly).
// Phase 3: all lanes walk edges together; lane covers channels c=lane, c=lane+64.
// Epilogue: fused bias+BN+ReLU via coefA/coefB.
// ---------------------------------------------------------------------------
__global__ __launch_bounds__(256) void gather_kernel(const float* __restrict__ hfeat,
                                                     const float* __restrict__ a_s,
                                                     const float* __restrict__ a_d,
                                                     const int* __restrict__ offsets,
                                                     const int* __restrict__ csr,
                                                     const float* __restrict__ coefA,
                                                     const float* __restrict__ coefB,
                                                     float* __restrict__ outp) {
    int wid  = (blockIdx.x * blockDim.x + threadIdx.x) >> 6;
    int lane = threadIdx.x & 63;
    if (wid >= N_NODES) return;
    int n = wid;
    int start = offsets[n], end = offsets[n + 1];
    float4 ad4 = *(const float4*)&a_d[n * 4];

    // Phase 1: max per head
    float m0 = -1e30f, m1 = -1e30f, m2 = -1e30f, m3 = -1e30f;
    for (int i = start + lane; i < end; i += 64) {
        int s = csr[i];
        float4 as4 = *(const float4*)&a_s[s * 4];
        float e0 = as4.x + ad4.x; e0 = e0 > 0.f ? e0 : 0.2f * e0;
        float e1 = as4.y + ad4.y; e1 = e1 > 0.f ? e1 : 0.2f * e1;
        float e2 = as4.z + ad4.z; e2 = e2 > 0.f ? e2 : 0.2f * e2;
        float e3 = as4.w + ad4.w; e3 = e3 > 0.f ? e3 : 0.2f * e3;
        m0 = fmaxf(m0, e0); m1 = fmaxf(m1, e1);
        m2 = fmaxf(m2, e2); m3 = fmaxf(m3, e3);
    }
#pragma unroll
    for (int off = 32; off > 0; off >>= 1) {
        m0 = fmaxf(m0, __shfl_xor(m0, off));
        m1 = fmaxf(m1, __shfl_xor(m1, off));
        m2 = fmaxf(m2, __shfl_xor(m2, off));
        m3 = fmaxf(m3, __shfl_xor(m3, off));
    }

    // Phase 2: exp-sum per head
    float d0 = 0.f, d1 = 0.f, d2 = 0.f, d3 = 0.f;
    for (int i = start + lane; i < end; i += 64) {
        int s = csr[i];
        float4 as4 = *(const float4*)&a_s[s * 4];
        float e0 = as4.x + ad4.x; e0 = e0 > 0.f ? e0 : 0.2f * e0;
        float e1 = as4.y + ad4.y; e1 = e1 > 0.f ? e1 : 0.2f * e1;
        float e2 = as4.z + ad4.z; e2 = e2 > 0.f ? e2 : 0.2f * e2;
        float e3 = as4.w + ad4.w; e3 = e3 > 0.f ? e3 : 0.2f * e3;
        d0 += __expf(e0 - m0); d1 += __expf(e1 - m1);
        d2 += __expf(e2 - m2); d3 += __expf(e3 - m3);
    }
#pragma unroll
    for (int off = 32; off > 0; off >>= 1) {
        d0 += __shfl_xor(d0, off);
        d1 += __shfl_xor(d1, off);
        d2 += __shfl_xor(d2, off);
        d3 += __shfl_xor(d3, off);
    }

    // Phase 3: weighted accumulate; lane covers channel c0=lane (head lane>>5)
    // and c1=lane+64 (head 2+(lane>>5)).
    bool lo = (lane < 32);
    int  h0 = lane >> 5;
    float mh0  = lo ? m0 : m1, mh1 = lo ? m2 : m3;
    float rd0  = 1.0f / ((lo ? d0 : d1) + 1e-16f);
    float rd1  = 1.0f / ((lo ? d2 : d3) + 1e-16f);
    float adh0 = lo ? ad4.x : ad4.y;
    float adh1 = lo ? ad4.z : ad4.w;

    float acc0 = 0.f, acc1 = 0.f;
    for (int i = start; i < end; i++) {
        int s = csr[i];
        float as0 = a_s[s * 4 + h0];
        float as1 = a_s[s * 4 + 2 + h0];
        float e0 = as0 + adh0; e0 = e0 > 0.f ? e0 : 0.2f * e0;
        float e1 = as1 + adh1; e1 = e1 > 0.f ? e1 : 0.2f * e1;
        float al0 = __expf(e0 - mh0) * rd0;
        float al1 = __expf(e1 - mh1) * rd1;
        const float* hr = hfeat + (size_t)s * HID;
        acc0 += hr[lane] * al0;
        acc1 += hr[lane + 64] * al1;
    }
    float o0 = acc0 * coefA[lane]      + coefB[lane];
    float o1 = acc1 * coefA[lane + 64] + coefB[lane + 64];
    outp[(size_t)n * HID + lane]      = o0 > 0.f ? o0 : 0.f;
    outp[(size_t)n * HID + 64 + lane] = o1 > 0.f ? o1 : 0.f;
}

// ---------------------------------------------------------------------------
extern "C" void kernel_launch(void* const* d_in, const int* in_sizes, int n_in,
                              void* d_out, int out_size, void* d_ws, size_t ws_size,
                              hipStream_t stream) {
    const float* x    = (const float*)d_in[0];
    const int*   ei   = (const int*)d_in[1];
    const float* W1   = (const float*)d_in[2];
    const float* as1  = (const float*)d_in[3];
    const float* ad1  = (const float*)d_in[4];
    const float* b1   = (const float*)d_in[5];
    const float* g1   = (const float*)d_in[6];
    const float* be1  = (const float*)d_in[7];
    const float* mn1  = (const float*)d_in[8];
    const float* vr1  = (const float*)d_in[9];
    const float* W2   = (const float*)d_in[10];
    const float* as2  = (const float*)d_in[11];
    const float* ad2  = (const float*)d_in[12];
    const float* b2   = (const float*)d_in[13];
    const float* g2   = (const float*)d_in[14];
    const float* be2  = (const float*)d_in[15];
    const float* mn2  = (const float*)d_in[16];
    const float* vr2  = (const float*)d_in[17];
    float* out = (float*)d_out;

    float* ws   = (float*)d_ws;
    float* h    = ws;                               // N*128
    float* x2   = h + (size_t)N_NODES * HID;        // N*128
    float* aS   = x2 + (size_t)N_NODES * HID;       // N*4
    float* aD   = aS + N_NODES * NH;                // N*4
    float* coef = aD + N_NODES * NH;                // 512
    int* counts  = (int*)(coef + 512);              // N
    int* offsets = counts + N_NODES;                // N+1
    int* cursor  = offsets + N_NODES + 1;           // N
    int* csr     = cursor + N_NODES;                // ETOT

    hipMemsetAsync(counts, 0, N_NODES * sizeof(int), stream);
    count_kernel<<<(ETOT + 255) / 256, 256, 0, stream>>>(ei, counts);
    scan_kernel<<<1, SCAN_T, 0, stream>>>(counts, offsets, cursor, N_NODES);
    scatter_kernel<<<(ETOT + 255) / 256, 256, 0, stream>>>(ei, cursor, csr);
    coef_kernel<<<1, 256, 0, stream>>>(b1, g1, be1, mn1, vr1, b2, g2, be2, mn2, vr2, coef);

    int gemmGrid = (N_NODES + GR - 1) / GR;       // 782
    int gatherGrid = (N_NODES + 3) / 4;           // 12500 (4 waves/block)
    int attGrid = (N_NODES * NH + 255) / 256;

    // Layer 1
    gemm_kernel<<<gemmGrid, 256, 0, stream>>>(x, W1, h, N_NODES, 256);
    attdot_kernel<<<attGrid, 256, 0, stream>>>(h, as1, ad1, aS, aD);
    gather_kernel<<<gatherGrid, 256, 0, stream>>>(h, aS, aD, offsets, csr,
                                                  coef, coef + 128, x2);
    // Layer 2
    gemm_kernel<<<gemmGrid, 256, 0, stream>>>(x2, W2, h, N_NODES, 128);
    attdot_kernel<<<attGrid, 256, 0, stream>>>(h, as2, ad2, aS, aD);
    gather_kernel<<<gatherGrid, 256, 0, stream>>>(h, aS, aD, offsets, csr,
                                                  coef + 256, coef + 384, out);
}

// Round 2
// 572.796 us; speedup vs baseline: 1.2421x; 1.2421x over previous
//
#include <hip/hip_runtime.h>
#include <math.h>

#define N_NODES 50000
#define EDGES   800000
#define ETOT    (EDGES + N_NODES)
#define HID     128
#define NH      4

// ---------------------------------------------------------------------------
// CSR build: counts -> hierarchical exclusive scan -> scatter
// ---------------------------------------------------------------------------
__global__ void count_kernel(const int* __restrict__ ei, int* __restrict__ counts) {
    int i = blockIdx.x * blockDim.x + threadIdx.x;
    if (i >= ETOT) return;
    int d = (i < EDGES) ? ei[EDGES + i] : (i - EDGES);
    atomicAdd(&counts[d], 1);
}

#define SCAN_B ((N_NODES + 255) / 256)   // 196 blocks of 256
__global__ __launch_bounds__(256) void scan1_kernel(const int* __restrict__ counts,
                                                    int* __restrict__ offsets,
                                                    int* __restrict__ blockSums) {
    __shared__ int sh[256];
    int t = threadIdx.x;
    int g = blockIdx.x * 256 + t;
    int v = (g < N_NODES) ? counts[g] : 0;
    sh[t] = v;
    __syncthreads();
    for (int off = 1; off < 256; off <<= 1) {
        int x = sh[t];
        int add = (t >= off) ? sh[t - off] : 0;
        __syncthreads();
        sh[t] = x + add;
        __syncthreads();
    }
    if (g < N_NODES) offsets[g] = sh[t] - v;  // exclusive within block
    if (t == 255) blockSums[blockIdx.x] = sh[255];
}

__global__ __launch_bounds__(256) void scan2_kernel(int* __restrict__ blockSums) {
    __shared__ int sh[256];
    int t = threadIdx.x;
    int v = (t < SCAN_B) ? blockSums[t] : 0;
    sh[t] = v;
    __syncthreads();
    for (int off = 1; off < 256; off <<= 1) {
        int x = sh[t];
        int add = (t >= off) ? sh[t - off] : 0;
        __syncthreads();
        sh[t] = x + add;
        __syncthreads();
    }
    if (t < SCAN_B) blockSums[t] = sh[t] - v;  // exclusive base per block
}

__global__ __launch_bounds__(256) void scan3_kernel(int* __restrict__ offsets,
                                                    const int* __restrict__ blockSums,
                                                    int* __restrict__ cursor) {
    int g = blockIdx.x * 256 + threadIdx.x;
    if (g < N_NODES) {
        int off = offsets[g] + blockSums[blockIdx.x];
        offsets[g] = off;
        cursor[g] = off;
    }
    if (g == 0) offsets[N_NODES] = ETOT;
}

__global__ void scatter_kernel(const int* __restrict__ ei, int* __restrict__ cursor,
                               int* __restrict__ csr) {
    int i = blockIdx.x * blockDim.x + threadIdx.x;
    if (i >= ETOT) return;
    int s, d;
    if (i < EDGES) { s = ei[i]; d = ei[EDGES + i]; }
    else           { s = d = i - EDGES; }
    int pos = atomicAdd(&cursor[d], 1);
    csr[pos] = s;
}

// ---------------------------------------------------------------------------
// Fold bias + BN(eval) into per-channel affine: out = relu(acc*A + B)
// coef layout: [A1(128) | B1(128) | A2(128) | B2(128)]
// ---------------------------------------------------------------------------
__global__ void coef_kernel(const float* __restrict__ b1, const float* __restrict__ g1,
                            const float* __restrict__ be1, const float* __restrict__ mn1,
                            const float* __restrict__ vr1,
                            const float* __restrict__ b2, const float* __restrict__ g2,
                            const float* __restrict__ be2, const float* __restrict__ mn2,
                            const float* __restrict__ vr2, float* __restrict__ coef) {
    int t = threadIdx.x;
    if (t < 128) {
        float sc = g1[t] * rsqrtf(vr1[t] + 1e-5f);
        coef[t]       = sc;
        coef[128 + t] = be1[t] + (b1[t] - mn1[t]) * sc;
    } else {
        int c = t - 128;
        float sc = g2[c] * rsqrtf(vr2[c] + 1e-5f);
        coef[256 + c] = sc;
        coef[384 + c] = be2[c] + (b2[c] - mn2[c]) * sc;
    }
}

// ---------------------------------------------------------------------------
// GEMM: Hout[N][128] = X[N][K] @ W[K][128], fp32.
// Block tile 128 rows x 128 cols, 256 threads, KC=32.
// Thread tile 8 rows x 8 cols: rows = rowg + 16*rr (rowg=t&15), cols = colg*8
// (colg=t>>4). Per kk: 8 scalar X reads (16-bank spread via +1 pad and strided
// rows) + 2 b128 W reads (contiguous) + 64 FMA -> VALU-bound, not LDS-bound.
// LDS 33.8 KB -> 4 blocks/CU (16 waves/CU).
// ---------------------------------------------------------------------------
#define GR 128
#define KC 32
__global__ __launch_bounds__(256) void gemm_kernel(const float* __restrict__ X,
                                                   const float* __restrict__ W,
                                                   float* __restrict__ Hout,
                                                   int Nrows, int K) {
    __shared__ float Xs[GR][KC + 1];   // 128 x 33
    __shared__ float Ws[KC][HID];      // 32 x 128
    int t = threadIdx.x;
    int rowBase = blockIdx.x * GR;
    int rowg = t & 15;
    int colg = t >> 4;

    float acc[8][8];
#pragma unroll
    for (int a = 0; a < 8; a++)
#pragma unroll
        for (int b = 0; b < 8; b++) acc[a][b] = 0.f;

    for (int k0 = 0; k0 < K; k0 += KC) {
        // stage X chunk: 128 rows x 32 k. s: row = s>>3, kq = s&7 (float4 each)
#pragma unroll
        for (int it = 0; it < 4; it++) {
            int s = t + it * 256;
            int row = s >> 3;
            int kq  = s & 7;
            int gr  = rowBase + row;
            float4 v = make_float4(0.f, 0.f, 0.f, 0.f);
            if (gr < Nrows) v = *(const float4*)&X[(size_t)gr * K + k0 + kq * 4];
            Xs[row][kq * 4 + 0] = v.x; Xs[row][kq * 4 + 1] = v.y;
            Xs[row][kq * 4 + 2] = v.z; Xs[row][kq * 4 + 3] = v.w;
        }
        // stage W chunk: 32 k x 128 cols
#pragma unroll
        for (int it = 0; it < 4; it++) {
            int s = t + it * 256;
            int kr = s >> 5;
            int cq = s & 31;
            *(float4*)&Ws[kr][cq * 4] = *(const float4*)&W[(size_t)(k0 + kr) * HID + cq * 4];
        }
        __syncthreads();
#pragma unroll 4
        for (int kk = 0; kk < KC; kk++) {
            float wv[8];
            *(float4*)&wv[0] = *(const float4*)&Ws[kk][colg * 8];
            *(float4*)&wv[4] = *(const float4*)&Ws[kk][colg * 8 + 4];
            float xv[8];
#pragma unroll
            for (int rr = 0; rr < 8; rr++) xv[rr] = Xs[rowg + 16 * rr][kk];
#pragma unroll
            for (int rr = 0; rr < 8; rr++)
#pragma unroll
                for (int cc = 0; cc < 8; cc++)
                    acc[rr][cc] = fmaf(xv[rr], wv[cc], acc[rr][cc]);
        }
        __syncthreads();
    }
#pragma unroll
    for (int rr = 0; rr < 8; rr++) {
        int row = rowBase + rowg + 16 * rr;
        if (row < Nrows) {
            *(float4*)&Hout[(size_t)row * HID + colg * 8]     = *(float4*)&acc[rr][0];
            *(float4*)&Hout[(size_t)row * HID + colg * 8 + 4] = *(float4*)&acc[rr][4];
        }
    }
}

// ---------------------------------------------------------------------------
// Per-node attention dots.
// ---------------------------------------------------------------------------
__global__ void attdot_kernel(const float* __restrict__ hfeat,
                              const float* __restrict__ att_src,
                              const float* __restrict__ att_dst,
                              float* __restrict__ a_s, float* __restrict__ a_d) {
    int idx = blockIdx.x * blockDim.x + threadIdx.x;
    if (idx >= N_NODES * NH) return;
    int n = idx >> 2, hd = idx & 3;
    const float4* hp = (const float4*)(hfeat + (size_t)n * HID + hd * 32);
    const float4* sp = (const float4*)(att_src + hd * 32);
    const float4* dp = (const float4*)(att_dst + hd * 32);
    float ss = 0.f, dd = 0.f;
#pragma unroll
    for (int i = 0; i < 8; i++) {
        float4 hv = hp[i], sv = sp[i], dv = dp[i];
        ss += hv.x * sv.x + hv.y * sv.y + hv.z * sv.z + hv.w * sv.w;
        dd += hv.x * dv.x + hv.y * dv.y + hv.z * dv.z + hv.w * dv.w;
    }
    a_s[idx] = ss;
    a_d[idx] = dd;
}

// ---------------------------------------------------------------------------
// alpha_kernel: one wave per dst node. 3 lane-parallel passes over incoming
// edges (max, exp-sum, write alpha[e][4]). Degrees ~Poisson(17), so each pass
// is ~1 iteration per lane.
// ---------------------------------------------------------------------------
__global__ __launch_bounds__(256) void alpha_kernel(const float* __restrict__ a_s,
                                                    const float* __restrict__ a_d,
                                                    const int* __restrict__ offsets,
                                                    const int* __restrict__ csr,
                                                    float* __restrict__ alpha) {
    int wid  = (blockIdx.x * blockDim.x + threadIdx.x) >> 6;
    int lane = threadIdx.x & 63;
    if (wid >= N_NODES) return;
    int n = wid;
    int start = offsets[n], end = offsets[n + 1];
    float4 ad4 = *(const float4*)&a_d[n * 4];

    float m0 = -1e30f, m1 = -1e30f, m2 = -1e30f, m3 = -1e30f;
    for (int i = start + lane; i < end; i += 64) {
        int s = csr[i];
        float4 as4 = *(const float4*)&a_s[s * 4];
        float e0 = as4.x + ad4.x; e0 = e0 > 0.f ? e0 : 0.2f * e0;
        float e1 = as4.y + ad4.y; e1 = e1 > 0.f ? e1 : 0.2f * e1;
        float e2 = as4.z + ad4.z; e2 = e2 > 0.f ? e2 : 0.2f * e2;
        float e3 = as4.w + ad4.w; e3 = e3 > 0.f ? e3 : 0.2f * e3;
        m0 = fmaxf(m0, e0); m1 = fmaxf(m1, e1);
        m2 = fmaxf(m2, e2); m3 = fmaxf(m3, e3);
    }
#pragma unroll
    for (int off = 32; off > 0; off >>= 1) {
        m0 = fmaxf(m0, __shfl_xor(m0, off));
        m1 = fmaxf(m1, __shfl_xor(m1, off));
        m2 = fmaxf(m2, __shfl_xor(m2, off));
        m3 = fmaxf(m3, __shfl_xor(m3, off));
    }

    float d0 = 0.f, d1 = 0.f, d2 = 0.f, d3 = 0.f;
    for (int i = start + lane; i < end; i += 64) {
        int s = csr[i];
        float4 as4 = *(const float4*)&a_s[s * 4];
        float e0 = as4.x + ad4.x; e0 = e0 > 0.f ? e0 : 0.2f * e0;
        float e1 = as4.y + ad4.y; e1 = e1 > 0.f ? e1 : 0.2f * e1;
        float e2 = as4.z + ad4.z; e2 = e2 > 0.f ? e2 : 0.2f * e2;
        float e3 = as4.w + ad4.w; e3 = e3 > 0.f ? e3 : 0.2f * e3;
        d0 += __expf(e0 - m0); d1 += __expf(e1 - m1);
        d2 += __expf(e2 - m2); d3 += __expf(e3 - m3);
    }
#pragma unroll
    for (int off = 32; off > 0; off >>= 1) {
        d0 += __shfl_xor(d0, off);
        d1 += __shfl_xor(d1, off);
        d2 += __shfl_xor(d2, off);
        d3 += __shfl_xor(d3, off);
    }
    float rd0 = 1.0f / (d0 + 1e-16f);
    float rd1 = 1.0f / (d1 + 1e-16f);
    float rd2 = 1.0f / (d2 + 1e-16f);
    float rd3 = 1.0f / (d3 + 1e-16f);

    for (int i = start + lane; i < end; i += 64) {
        int s = csr[i];
        float4 as4 = *(const float4*)&a_s[s * 4];
        float e0 = as4.x + ad4.x; e0 = e0 > 0.f ? e0 : 0.2f * e0;
        float e1 = as4.y + ad4.y; e1 = e1 > 0.f ? e1 : 0.2f * e1;
        float e2 = as4.z + ad4.z; e2 = e2 > 0.f ? e2 : 0.2f * e2;
        float e3 = as4.w + ad4.w; e3 = e3 > 0.f ? e3 : 0.2f * e3;
        float4 al;
        al.x = __expf(e0 - m0) * rd0;
        al.y = __expf(e1 - m1) * rd1;
        al.z = __expf(e2 - m2) * rd2;
        al.w = __expf(e3 - m3) * rd3;
        *(float4*)&alpha[(size_t)i * 4] = al;
    }
}

// ---------------------------------------------------------------------------
// agg_kernel: one wave per dst node. Per edge: uniform csr/alpha loads
// (broadcast) + 2 coalesced h-row loads + 2 FMA per lane. Fused bias+BN+ReLU.
// ---------------------------------------------------------------------------
__global__ __launch_bounds__(256) void agg_kernel(const float* __restrict__ hfeat,
                                                  const float* __restrict__ alpha,
                                                  const int* __restrict__ offsets,
                                                  const int* __restrict__ csr,
                                                  const float* __restrict__ coefA,
                                                  const float* __restrict__ coefB,
                                                  float* __restrict__ outp) {
    int wid  = (blockIdx.x * blockDim.x + threadIdx.x) >> 6;
    int lane = threadIdx.x & 63;
    if (wid >= N_NODES) return;
    int n = wid;
    int start = offsets[n], end = offsets[n + 1];
    bool lo = (lane < 32);

    float acc0 = 0.f, acc1 = 0.f;
    for (int i = start; i < end; i++) {
        int s = csr[i];
        float4 a4 = *(const float4*)&alpha[(size_t)i * 4];
        float al0 = lo ? a4.x : a4.y;
        float al1 = lo ? a4.z : a4.w;
        const float* hr = hfeat + (size_t)s * HID;
        acc0 = fmaf(hr[lane], al0, acc0);
        acc1 = fmaf(hr[lane + 64], al1, acc1);
    }
    float o0 = acc0 * coefA[lane]      + coefB[lane];
    float o1 = acc1 * coefA[lane + 64] + coefB[lane + 64];
    outp[(size_t)n * HID + lane]      = o0 > 0.f ? o0 : 0.f;
    outp[(size_t)n * HID + 64 + lane] = o1 > 0.f ? o1 : 0.f;
}

// ---------------------------------------------------------------------------
extern "C" void kernel_launch(void* const* d_in, const int* in_sizes, int n_in,
                              void* d_out, int out_size, void* d_ws, size_t ws_size,
                              hipStream_t stream) {
    const float* x    = (const float*)d_in[0];
    const int*   ei   = (const int*)d_in[1];
    const float* W1   = (const float*)d_in[2];
    const float* as1  = (const float*)d_in[3];
    const float* ad1  = (const float*)d_in[4];
    const float* b1   = (const float*)d_in[5];
    const float* g1   = (const float*)d_in[6];
    const float* be1  = (const float*)d_in[7];
    const float* mn1  = (const float*)d_in[8];
    const float* vr1  = (const float*)d_in[9];
    const float* W2   = (const float*)d_in[10];
    const float* as2  = (const float*)d_in[11];
    const float* ad2  = (const float*)d_in[12];
    const float* b2   = (const float*)d_in[13];
    const float* g2   = (const float*)d_in[14];
    const float* be2  = (const float*)d_in[15];
    const float* mn2  = (const float*)d_in[16];
    const float* vr2  = (const float*)d_in[17];
    float* out = (float*)d_out;

    float* ws    = (float*)d_ws;
    float* h     = ws;                               // N*128
    float* x2    = h + (size_t)N_NODES * HID;        // N*128
    float* aS    = x2 + (size_t)N_NODES * HID;       // N*4
    float* aD    = aS + N_NODES * NH;                // N*4
    float* alpha = aD + N_NODES * NH;                // ETOT*4
    float* coef  = alpha + (size_t)ETOT * 4;         // 512
    int* counts    = (int*)(coef + 512);             // N
    int* offsets   = counts + N_NODES;               // N+1
    int* cursor    = offsets + N_NODES + 1;          // N
    int* blockSums = cursor + N_NODES;               // SCAN_B
    int* csr       = blockSums + 256;                // ETOT

    hipMemsetAsync(counts, 0, N_NODES * sizeof(int), stream);
    count_kernel<<<(ETOT + 255) / 256, 256, 0, stream>>>(ei, counts);
    scan1_kernel<<<SCAN_B, 256, 0, stream>>>(counts, offsets, blockSums);
    scan2_kernel<<<1, 256, 0, stream>>>(blockSums);
    scan3_kernel<<<SCAN_B, 256, 0, stream>>>(offsets, blockSums, cursor);
    scatter_kernel<<<(ETOT + 255) / 256, 256, 0, stream>>>(ei, cursor, csr);
    coef_kernel<<<1, 256, 0, stream>>>(b1, g1, be1, mn1, vr1, b2, g2, be2, mn2, vr2, coef);

    int gemmGrid = (N_NODES + GR - 1) / GR;       // 391
    int nodeGrid = (N_NODES + 3) / 4;             // 12500 (4 waves/block)
    int attGrid  = (N_NODES * NH + 255) / 256;

    // Layer 1
    gemm_kernel<<<gemmGrid, 256, 0, stream>>>(x, W1, h, N_NODES, 256);
    attdot_kernel<<<attGrid, 256, 0, stream>>>(h, as1, ad1, aS, aD);
    alpha_kernel<<<nodeGrid, 256, 0, stream>>>(aS, aD, offsets, csr, alpha);
    agg_kernel<<<nodeGrid, 256, 0, stream>>>(h, alpha, offsets, csr,
                                             coef, coef + 128, x2);
    // Layer 2
    gemm_kernel<<<gemmGrid, 256, 0, stream>>>(x2, W2, h, N_NODES, 128);
    attdot_kernel<<<attGrid, 256, 0, stream>>>(h, as2, ad2, aS, aD);
    alpha_kernel<<<nodeGrid, 256, 0, stream>>>(aS, aD, offsets, csr, alpha);
    agg_kernel<<<nodeGrid, 256, 0, stream>>>(h, alpha, offsets, csr,
                                             coef + 256, coef + 384, out);
}

// Round 3
// 514.476 us; speedup vs baseline: 1.3829x; 1.1134x over previous
//
#include <hip/hip_runtime.h>
#include <math.h>

#define N_NODES 50000
#define EDGES   800000
#define ETOT    (EDGES + N_NODES)
#define HID     128
#define NH      4

// ---------------------------------------------------------------------------
// CSR build: counts -> hierarchical exclusive scan -> scatter
// ---------------------------------------------------------------------------
__global__ void count_kernel(const int* __restrict__ ei, int* __restrict__ counts) {
    int i = blockIdx.x * blockDim.x + threadIdx.x;
    if (i >= ETOT) return;
    int d = (i < EDGES) ? ei[EDGES + i] : (i - EDGES);
    atomicAdd(&counts[d], 1);
}

#define SCAN_B ((N_NODES + 255) / 256)   // 196 blocks of 256
__global__ __launch_bounds__(256) void scan1_kernel(const int* __restrict__ counts,
                                                    int* __restrict__ offsets,
                                                    int* __restrict__ blockSums) {
    __shared__ int sh[256];
    int t = threadIdx.x;
    int g = blockIdx.x * 256 + t;
    int v = (g < N_NODES) ? counts[g] : 0;
    sh[t] = v;
    __syncthreads();
    for (int off = 1; off < 256; off <<= 1) {
        int x = sh[t];
        int add = (t >= off) ? sh[t - off] : 0;
        __syncthreads();
        sh[t] = x + add;
        __syncthreads();
    }
    if (g < N_NODES) offsets[g] = sh[t] - v;  // exclusive within block
    if (t == 255) blockSums[blockIdx.x] = sh[255];
}

__global__ __launch_bounds__(256) void scan2_kernel(int* __restrict__ blockSums) {
    __shared__ int sh[256];
    int t = threadIdx.x;
    int v = (t < SCAN_B) ? blockSums[t] : 0;
    sh[t] = v;
    __syncthreads();
    for (int off = 1; off < 256; off <<= 1) {
        int x = sh[t];
        int add = (t >= off) ? sh[t - off] : 0;
        __syncthreads();
        sh[t] = x + add;
        __syncthreads();
    }
    if (t < SCAN_B) blockSums[t] = sh[t] - v;  // exclusive base per block
}

__global__ __launch_bounds__(256) void scan3_kernel(int* __restrict__ offsets,
                                                    const int* __restrict__ blockSums,
                                                    int* __restrict__ cursor) {
    int g = blockIdx.x * 256 + threadIdx.x;
    if (g < N_NODES) {
        int off = offsets[g] + blockSums[blockIdx.x];
        offsets[g] = off;
        cursor[g] = off;
    }
    if (g == 0) offsets[N_NODES] = ETOT;
}

__global__ void scatter_kernel(const int* __restrict__ ei, int* __restrict__ cursor,
                               int* __restrict__ csr) {
    int i = blockIdx.x * blockDim.x + threadIdx.x;
    if (i >= ETOT) return;
    int s, d;
    if (i < EDGES) { s = ei[i]; d = ei[EDGES + i]; }
    else           { s = d = i - EDGES; }
    int pos = atomicAdd(&cursor[d], 1);
    csr[pos] = s;
}

// ---------------------------------------------------------------------------
// Fold bias + BN(eval) into per-channel affine: out = relu(acc*A + B)
// coef layout: [A1(128) | B1(128) | A2(128) | B2(128)]
// ---------------------------------------------------------------------------
__global__ void coef_kernel(const float* __restrict__ b1, const float* __restrict__ g1,
                            const float* __restrict__ be1, const float* __restrict__ mn1,
                            const float* __restrict__ vr1,
                            const float* __restrict__ b2, const float* __restrict__ g2,
                            const float* __restrict__ be2, const float* __restrict__ mn2,
                            const float* __restrict__ vr2, float* __restrict__ coef) {
    int t = threadIdx.x;
    if (t < 128) {
        float sc = g1[t] * rsqrtf(vr1[t] + 1e-5f);
        coef[t]       = sc;
        coef[128 + t] = be1[t] + (b1[t] - mn1[t]) * sc;
    } else {
        int c = t - 128;
        float sc = g2[c] * rsqrtf(vr2[c] + 1e-5f);
        coef[256 + c] = sc;
        coef[384 + c] = be2[c] + (b2[c] - mn2[c]) * sc;
    }
}

// ---------------------------------------------------------------------------
// GEMM + fused attention dots.
// Block tile 128x128, 256 threads, KC=32, thread tile 8x8 (rows rowg+16*rr,
// cols colg*8). Wave w holds cols [w*32,(w+1)*32) == head w exactly, so
// a_s/a_d reduce with 2 shuffle-xors (lanes rowg, rowg+16, rowg+32, rowg+48).
// ---------------------------------------------------------------------------
#define GR 128
#define KC 32
__global__ __launch_bounds__(256) void gemm_att_kernel(const float* __restrict__ X,
                                                       const float* __restrict__ W,
                                                       const float* __restrict__ att_src,
                                                       const float* __restrict__ att_dst,
                                                       float* __restrict__ Hout,
                                                       float* __restrict__ aS,
                                                       float* __restrict__ aD,
                                                       int Nrows, int K) {
    __shared__ float Xs[GR][KC + 1];   // 128 x 33
    __shared__ float Ws[KC][HID];      // 32 x 128
    int t = threadIdx.x;
    int rowBase = blockIdx.x * GR;
    int rowg = t & 15;
    int colg = t >> 4;

    float acc[8][8];
#pragma unroll
    for (int a = 0; a < 8; a++)
#pragma unroll
        for (int b = 0; b < 8; b++) acc[a][b] = 0.f;

    for (int k0 = 0; k0 < K; k0 += KC) {
#pragma unroll
        for (int it = 0; it < 4; it++) {
            int s = t + it * 256;
            int row = s >> 3;
            int kq  = s & 7;
            int gr  = rowBase + row;
            float4 v = make_float4(0.f, 0.f, 0.f, 0.f);
            if (gr < Nrows) v = *(const float4*)&X[(size_t)gr * K + k0 + kq * 4];
            Xs[row][kq * 4 + 0] = v.x; Xs[row][kq * 4 + 1] = v.y;
            Xs[row][kq * 4 + 2] = v.z; Xs[row][kq * 4 + 3] = v.w;
        }
#pragma unroll
        for (int it = 0; it < 4; it++) {
            int s = t + it * 256;
            int kr = s >> 5;
            int cq = s & 31;
            *(float4*)&Ws[kr][cq * 4] = *(const float4*)&W[(size_t)(k0 + kr) * HID + cq * 4];
        }
        __syncthreads();
#pragma unroll 4
        for (int kk = 0; kk < KC; kk++) {
            float wv[8];
            *(float4*)&wv[0] = *(const float4*)&Ws[kk][colg * 8];
            *(float4*)&wv[4] = *(const float4*)&Ws[kk][colg * 8 + 4];
            float xv[8];
#pragma unroll
            for (int rr = 0; rr < 8; rr++) xv[rr] = Xs[rowg + 16 * rr][kk];
#pragma unroll
            for (int rr = 0; rr < 8; rr++)
#pragma unroll
                for (int cc = 0; cc < 8; cc++)
                    acc[rr][cc] = fmaf(xv[rr], wv[cc], acc[rr][cc]);
        }
        __syncthreads();
    }

    // store H
#pragma unroll
    for (int rr = 0; rr < 8; rr++) {
        int row = rowBase + rowg + 16 * rr;
        if (row < Nrows) {
            *(float4*)&Hout[(size_t)row * HID + colg * 8]     = *(float4*)&acc[rr][0];
            *(float4*)&Hout[(size_t)row * HID + colg * 8 + 4] = *(float4*)&acc[rr][4];
        }
    }

    // fused attention dots: head = wave id
    int w  = t >> 6;
    int cq = colg & 3;
    float asv[8], adv[8];
    *(float4*)&asv[0] = *(const float4*)&att_src[w * 32 + cq * 8];
    *(float4*)&asv[4] = *(const float4*)&att_src[w * 32 + cq * 8 + 4];
    *(float4*)&adv[0] = *(const float4*)&att_dst[w * 32 + cq * 8];
    *(float4*)&adv[4] = *(const float4*)&att_dst[w * 32 + cq * 8 + 4];
#pragma unroll
    for (int rr = 0; rr < 8; rr++) {
        float ds = 0.f, dd = 0.f;
#pragma unroll
        for (int cc = 0; cc < 8; cc++) {
            ds = fmaf(acc[rr][cc], asv[cc], ds);
            dd = fmaf(acc[rr][cc], adv[cc], dd);
        }
        ds += __shfl_xor(ds, 16); ds += __shfl_xor(ds, 32);
        dd += __shfl_xor(dd, 16); dd += __shfl_xor(dd, 32);
        if (cq == 0) {
            int row = rowBase + rowg + 16 * rr;
            if (row < Nrows) {
                aS[row * 4 + w] = ds;
                aD[row * 4 + w] = dd;
            }
        }
    }
}

// ---------------------------------------------------------------------------
// alpha_kernel: one wave per dst node, SINGLE pass over memory.
// Cache up to 2 lane-strided chunks (deg <= 128 covers everything here;
// generic fallback loops keep correctness for larger degrees).
// ---------------------------------------------------------------------------
__global__ __launch_bounds__(256) void alpha_kernel(const float* __restrict__ a_s,
                                                    const float* __restrict__ a_d,
                                                    const int* __restrict__ offsets,
                                                    const int* __restrict__ csr,
                                                    float* __restrict__ alpha) {
    int wid  = (blockIdx.x * blockDim.x + threadIdx.x) >> 6;
    int lane = threadIdx.x & 63;
    if (wid >= N_NODES) return;
    int n = wid;
    int start = offsets[n], end = offsets[n + 1];
    float4 ad4 = *(const float4*)&a_d[n * 4];

    int i0 = start + lane;
    int i1 = i0 + 64;
    bool v0 = i0 < end, v1 = i1 < end;

    float e00 = -1e30f, e01 = -1e30f, e02 = -1e30f, e03 = -1e30f;
    float e10 = -1e30f, e11 = -1e30f, e12 = -1e30f, e13 = -1e30f;
    if (v0) {
        float4 as4 = *(const float4*)&a_s[csr[i0] * 4];
        e00 = as4.x + ad4.x; e00 = e00 > 0.f ? e00 : 0.2f * e00;
        e01 = as4.y + ad4.y; e01 = e01 > 0.f ? e01 : 0.2f * e01;
        e02 = as4.z + ad4.z; e02 = e02 > 0.f ? e02 : 0.2f * e02;
        e03 = as4.w + ad4.w; e03 = e03 > 0.f ? e03 : 0.2f * e03;
    }
    if (v1) {
        float4 as4 = *(const float4*)&a_s[csr[i1] * 4];
        e10 = as4.x + ad4.x; e10 = e10 > 0.f ? e10 : 0.2f * e10;
        e11 = as4.y + ad4.y; e11 = e11 > 0.f ? e11 : 0.2f * e11;
        e12 = as4.z + ad4.z; e12 = e12 > 0.f ? e12 : 0.2f * e12;
        e13 = as4.w + ad4.w; e13 = e13 > 0.f ? e13 : 0.2f * e13;
    }
    float m0 = fmaxf(e00, e10), m1 = fmaxf(e01, e11);
    float m2 = fmaxf(e02, e12), m3 = fmaxf(e03, e13);
    for (int i = start + 128 + lane; i < end; i += 64) {   // rare fallback
        float4 as4 = *(const float4*)&a_s[csr[i] * 4];
        float f0 = as4.x + ad4.x; f0 = f0 > 0.f ? f0 : 0.2f * f0;
        float f1 = as4.y + ad4.y; f1 = f1 > 0.f ? f1 : 0.2f * f1;
        float f2 = as4.z + ad4.z; f2 = f2 > 0.f ? f2 : 0.2f * f2;
        float f3 = as4.w + ad4.w; f3 = f3 > 0.f ? f3 : 0.2f * f3;
        m0 = fmaxf(m0, f0); m1 = fmaxf(m1, f1);
        m2 = fmaxf(m2, f2); m3 = fmaxf(m3, f3);
    }
#pragma unroll
    for (int off = 32; off > 0; off >>= 1) {
        m0 = fmaxf(m0, __shfl_xor(m0, off));
        m1 = fmaxf(m1, __shfl_xor(m1, off));
        m2 = fmaxf(m2, __shfl_xor(m2, off));
        m3 = fmaxf(m3, __shfl_xor(m3, off));
    }

    // exp (cached; invalid lanes give exp(-inf)=0)
    float x00 = __expf(e00 - m0), x01 = __expf(e01 - m1);
    float x02 = __expf(e02 - m2), x03 = __expf(e03 - m3);
    float x10 = __expf(e10 - m0), x11 = __expf(e11 - m1);
    float x12 = __expf(e12 - m2), x13 = __expf(e13 - m3);
    float d0 = x00 + x10, d1 = x01 + x11, d2 = x02 + x12, d3 = x03 + x13;
    for (int i = start + 128 + lane; i < end; i += 64) {   // rare fallback
        float4 as4 = *(const float4*)&a_s[csr[i] * 4];
        float f0 = as4.x + ad4.x; f0 = f0 > 0.f ? f0 : 0.2f * f0;
        float f1 = as4.y + ad4.y; f1 = f1 > 0.f ? f1 : 0.2f * f1;
        float f2 = as4.z + ad4.z; f2 = f2 > 0.f ? f2 : 0.2f * f2;
        float f3 = as4.w + ad4.w; f3 = f3 > 0.f ? f3 : 0.2f * f3;
        d0 += __expf(f0 - m0); d1 += __expf(f1 - m1);
        d2 += __expf(f2 - m2); d3 += __expf(f3 - m3);
    }
#pragma unroll
    for (int off = 32; off > 0; off >>= 1) {
        d0 += __shfl_xor(d0, off);
        d1 += __shfl_xor(d1, off);
        d2 += __shfl_xor(d2, off);
        d3 += __shfl_xor(d3, off);
    }
    float rd0 = 1.0f / (d0 + 1e-16f);
    float rd1 = 1.0f / (d1 + 1e-16f);
    float rd2 = 1.0f / (d2 + 1e-16f);
    float rd3 = 1.0f / (d3 + 1e-16f);

    if (v0) {
        float4 al; al.x = x00 * rd0; al.y = x01 * rd1; al.z = x02 * rd2; al.w = x03 * rd3;
        *(float4*)&alpha[(size_t)i0 * 4] = al;
    }
    if (v1) {
        float4 al; al.x = x10 * rd0; al.y = x11 * rd1; al.z = x12 * rd2; al.w = x13 * rd3;
        *(float4*)&alpha[(size_t)i1 * 4] = al;
    }
    for (int i = start + 128 + lane; i < end; i += 64) {   // rare fallback
        float4 as4 = *(const float4*)&a_s[csr[i] * 4];
        float f0 = as4.x + ad4.x; f0 = f0 > 0.f ? f0 : 0.2f * f0;
        float f1 = as4.y + ad4.y; f1 = f1 > 0.f ? f1 : 0.2f * f1;
        float f2 = as4.z + ad4.z; f2 = f2 > 0.f ? f2 : 0.2f * f2;
        float f3 = as4.w + ad4.w; f3 = f3 > 0.f ? f3 : 0.2f * f3;
        float4 al;
        al.x = __expf(f0 - m0) * rd0; al.y = __expf(f1 - m1) * rd1;
        al.z = __expf(f2 - m2) * rd2; al.w = __expf(f3 - m3) * rd3;
        *(float4*)&alpha[(size_t)i * 4] = al;
    }
}

// ---------------------------------------------------------------------------
// agg_kernel: TWO waves per dst node (half = 64 channels each), edge loop
// unrolled x4 with loads batched up front for memory-level parallelism.
// Per lane: channel c = half*64 + lane, head h0 = c>>5 (compile-time-constant
// per lane). Fused bias+BN+ReLU epilogue.
// ---------------------------------------------------------------------------
__global__ __launch_bounds__(256) void agg_kernel(const float* __restrict__ hfeat,
                                                  const float* __restrict__ alpha,
                                                  const int* __restrict__ offsets,
                                                  const int* __restrict__ csr,
                                                  const float* __restrict__ coefA,
                                                  const float* __restrict__ coefB,
                                                  float* __restrict__ outp) {
    int gw   = (blockIdx.x * blockDim.x + threadIdx.x) >> 6;  // global wave
    int lane = threadIdx.x & 63;
    if (gw >= 2 * N_NODES) return;
    int n    = gw >> 1;
    int half = gw & 1;
    int c    = half * 64 + lane;
    int h0   = c >> 5;
    int start = offsets[n], end = offsets[n + 1];

    float acc = 0.f;
    int i = start;
    for (; i + 3 < end; i += 4) {
        int sA = csr[i], sB = csr[i + 1], sC = csr[i + 2], sD = csr[i + 3];
        float alA = alpha[(size_t)(i    ) * 4 + h0];
        float alB = alpha[(size_t)(i + 1) * 4 + h0];
        float alC = alpha[(size_t)(i + 2) * 4 + h0];
        float alD = alpha[(size_t)(i + 3) * 4 + h0];
        float hA = hfeat[(size_t)sA * HID + c];
        float hB = hfeat[(size_t)sB * HID + c];
        float hC = hfeat[(size_t)sC * HID + c];
        float hD = hfeat[(size_t)sD * HID + c];
        acc = fmaf(hA, alA, acc);
        acc = fmaf(hB, alB, acc);
        acc = fmaf(hC, alC, acc);
        acc = fmaf(hD, alD, acc);
    }
    for (; i < end; i++) {
        int s = csr[i];
        float al = alpha[(size_t)i * 4 + h0];
        acc = fmaf(hfeat[(size_t)s * HID + c], al, acc);
    }
    float o = acc * coefA[c] + coefB[c];
    outp[(size_t)n * HID + c] = o > 0.f ? o : 0.f;
}

// ---------------------------------------------------------------------------
extern "C" void kernel_launch(void* const* d_in, const int* in_sizes, int n_in,
                              void* d_out, int out_size, void* d_ws, size_t ws_size,
                              hipStream_t stream) {
    const float* x    = (const float*)d_in[0];
    const int*   ei   = (const int*)d_in[1];
    const float* W1   = (const float*)d_in[2];
    const float* as1  = (const float*)d_in[3];
    const float* ad1  = (const float*)d_in[4];
    const float* b1   = (const float*)d_in[5];
    const float* g1   = (const float*)d_in[6];
    const float* be1  = (const float*)d_in[7];
    const float* mn1  = (const float*)d_in[8];
    const float* vr1  = (const float*)d_in[9];
    const float* W2   = (const float*)d_in[10];
    const float* as2  = (const float*)d_in[11];
    const float* ad2  = (const float*)d_in[12];
    const float* b2   = (const float*)d_in[13];
    const float* g2   = (const float*)d_in[14];
    const float* be2  = (const float*)d_in[15];
    const float* mn2  = (const float*)d_in[16];
    const float* vr2  = (const float*)d_in[17];
    float* out = (float*)d_out;

    float* ws    = (float*)d_ws;
    float* h     = ws;                               // N*128
    float* x2    = h + (size_t)N_NODES * HID;        // N*128
    float* aS    = x2 + (size_t)N_NODES * HID;       // N*4
    float* aD    = aS + N_NODES * NH;                // N*4
    float* alpha = aD + N_NODES * NH;                // ETOT*4
    float* coef  = alpha + (size_t)ETOT * 4;         // 512
    int* counts    = (int*)(coef + 512);             // N
    int* offsets   = counts + N_NODES;               // N+1
    int* cursor    = offsets + N_NODES + 1;          // N
    int* blockSums = cursor + N_NODES;               // SCAN_B
    int* csr       = blockSums + 256;                // ETOT

    hipMemsetAsync(counts, 0, N_NODES * sizeof(int), stream);
    count_kernel<<<(ETOT + 255) / 256, 256, 0, stream>>>(ei, counts);
    scan1_kernel<<<SCAN_B, 256, 0, stream>>>(counts, offsets, blockSums);
    scan2_kernel<<<1, 256, 0, stream>>>(blockSums);
    scan3_kernel<<<SCAN_B, 256, 0, stream>>>(offsets, blockSums, cursor);
    scatter_kernel<<<(ETOT + 255) / 256, 256, 0, stream>>>(ei, cursor, csr);
    coef_kernel<<<1, 256, 0, stream>>>(b1, g1, be1, mn1, vr1, b2, g2, be2, mn2, vr2, coef);

    int gemmGrid  = (N_NODES + GR - 1) / GR;        // 391
    int alphaGrid = (N_NODES + 3) / 4;              // 12500
    int aggGrid   = (2 * N_NODES + 3) / 4;          // 25000

    // Layer 1
    gemm_att_kernel<<<gemmGrid, 256, 0, stream>>>(x, W1, as1, ad1, h, aS, aD,
                                                  N_NODES, 256);
    alpha_kernel<<<alphaGrid, 256, 0, stream>>>(aS, aD, offsets, csr, alpha);
    agg_kernel<<<aggGrid, 256, 0, stream>>>(h, alpha, offsets, csr,
                                            coef, coef + 128, x2);
    // Layer 2
    gemm_att_kernel<<<gemmGrid, 256, 0, stream>>>(x2, W2, as2, ad2, h, aS, aD,
                                                  N_NODES, 128);
    alpha_kernel<<<alphaGrid, 256, 0, stream>>>(aS, aD, offsets, csr, alpha);
    agg_kernel<<<aggGrid, 256, 0, stream>>>(h, alpha, offsets, csr,
                                            coef + 256, coef + 384, out);
}

// Round 4
// 387.773 us; speedup vs baseline: 1.8347x; 1.3267x over previous
//
#include <hip/hip_runtime.h>
#include <math.h>

#define N_NODES 50000
#define EDGES   800000
#define ETOT    (EDGES + N_NODES)
#define HID     128
#define NH      4

typedef __attribute__((ext_vector_type(8))) short short8;
typedef __attribute__((ext_vector_type(4))) float floatx4;

__device__ inline unsigned short f2bf(float f) {
    unsigned int u = __float_as_uint(f);
    u = u + 0x7FFFu + ((u >> 16) & 1u);   // RNE
    return (unsigned short)(u >> 16);
}

// ---------------------------------------------------------------------------
// CSR build: counts -> hierarchical exclusive scan -> scatter
// ---------------------------------------------------------------------------
__global__ void count_kernel(const int* __restrict__ ei, int* __restrict__ counts) {
    int i = blockIdx.x * blockDim.x + threadIdx.x;
    if (i >= ETOT) return;
    int d = (i < EDGES) ? ei[EDGES + i] : (i - EDGES);
    atomicAdd(&counts[d], 1);
}

#define SCAN_B ((N_NODES + 255) / 256)   // 196 blocks of 256
__global__ __launch_bounds__(256) void scan1_kernel(const int* __restrict__ counts,
                                                    int* __restrict__ offsets,
                                                    int* __restrict__ blockSums) {
    __shared__ int sh[256];
    int t = threadIdx.x;
    int g = blockIdx.x * 256 + t;
    int v = (g < N_NODES) ? counts[g] : 0;
    sh[t] = v;
    __syncthreads();
    for (int off = 1; off < 256; off <<= 1) {
        int x = sh[t];
        int add = (t >= off) ? sh[t - off] : 0;
        __syncthreads();
        sh[t] = x + add;
        __syncthreads();
    }
    if (g < N_NODES) offsets[g] = sh[t] - v;
    if (t == 255) blockSums[blockIdx.x] = sh[255];
}

__global__ __launch_bounds__(256) void scan2_kernel(int* __restrict__ blockSums) {
    __shared__ int sh[256];
    int t = threadIdx.x;
    int v = (t < SCAN_B) ? blockSums[t] : 0;
    sh[t] = v;
    __syncthreads();
    for (int off = 1; off < 256; off <<= 1) {
        int x = sh[t];
        int add = (t >= off) ? sh[t - off] : 0;
        __syncthreads();
        sh[t] = x + add;
        __syncthreads();
    }
    if (t < SCAN_B) blockSums[t] = sh[t] - v;
}

__global__ __launch_bounds__(256) void scan3_kernel(int* __restrict__ offsets,
                                                    const int* __restrict__ blockSums,
                                                    int* __restrict__ cursor) {
    int g = blockIdx.x * 256 + threadIdx.x;
    if (g < N_NODES) {
        int off = offsets[g] + blockSums[blockIdx.x];
        offsets[g] = off;
        cursor[g] = off;
    }
    if (g == 0) offsets[N_NODES] = ETOT;
}

__global__ void scatter_kernel(const int* __restrict__ ei, int* __restrict__ cursor,
                               int* __restrict__ csr) {
    int i = blockIdx.x * blockDim.x + threadIdx.x;
    if (i >= ETOT) return;
    int s, d;
    if (i < EDGES) { s = ei[i]; d = ei[EDGES + i]; }
    else           { s = d = i - EDGES; }
    int pos = atomicAdd(&cursor[d], 1);
    csr[pos] = s;
}

// ---------------------------------------------------------------------------
// coef: fold bias+BN into per-channel affine. [A1|B1|A2|B2] (128 each)
// ---------------------------------------------------------------------------
__global__ void coef_kernel(const float* __restrict__ b1, const float* __restrict__ g1,
                            const float* __restrict__ be1, const float* __restrict__ mn1,
                            const float* __restrict__ vr1,
                            const float* __restrict__ b2, const float* __restrict__ g2,
                            const float* __restrict__ be2, const float* __restrict__ mn2,
                            const float* __restrict__ vr2, float* __restrict__ coef) {
    int t = threadIdx.x;
    if (t < 128) {
        float sc = g1[t] * rsqrtf(vr1[t] + 1e-5f);
        coef[t]       = sc;
        coef[128 + t] = be1[t] + (b1[t] - mn1[t]) * sc;
    } else {
        int c = t - 128;
        float sc = g2[c] * rsqrtf(vr2[c] + 1e-5f);
        coef[256 + c] = sc;
        coef[384 + c] = be2[c] + (b2[c] - mn2[c]) * sc;
    }
}

// ---------------------------------------------------------------------------
// W transpose + bf16 convert: Wt[n][k] = bf16(W[k][n])
// ---------------------------------------------------------------------------
__global__ void wtrans_kernel(const float* __restrict__ W1, const float* __restrict__ W2,
                              unsigned short* __restrict__ Wt1, unsigned short* __restrict__ Wt2) {
    int i = blockIdx.x * 256 + threadIdx.x;
    if (i < 256 * 128) { int k = i >> 7, n = i & 127; Wt1[(size_t)n * 256 + k] = f2bf(W1[i]); }
    if (i < 128 * 128) { int k = i >> 7, n = i & 127; Wt2[(size_t)n * 128 + k] = f2bf(W2[i]); }
}

// ---------------------------------------------------------------------------
// MFMA GEMM (bf16 in, fp32 acc) + fused attention dots + bf16 H output.
// Block: 256 thr (4 waves), tile 128 rows x 128 cols, KC=64 staged.
// Wave w: rows [w*32, w*32+32) as 2 row-tiles x 8 col-tiles of 16x16x32 MFMA.
// Layouts (HW-verified): A[m=lane&15][k=quad*8+j]; B[k][n=lane&15];
// C/D: row=quad*4+reg, col=lane&15.
// Epilogue: acc -> LDS (bf16) -> coalesced 16B global stores; att dots fused
// into the readback (8 cols/lane are within one head; reduce via xor 1,2).
// ---------------------------------------------------------------------------
#define GR   128
#define KC   64
#define PADK 88     // bf16 elems/row: 176B, 16B-aligned, ~2-way banks
#define PADH 136    // 272B rows for the H repack

union Smem {
    struct { unsigned short Xs[GR][PADK]; unsigned short Ws[HID][PADK]; } s;
    unsigned short Hs[GR][PADH];
};

template<bool XBF16>
__global__ __launch_bounds__(256) void gemm_att_kernel(const void* __restrict__ Xv,
                                                       const unsigned short* __restrict__ Wt,
                                                       const float* __restrict__ att_src,
                                                       const float* __restrict__ att_dst,
                                                       unsigned short* __restrict__ Hout,
                                                       float* __restrict__ aS,
                                                       float* __restrict__ aD, int K) {
    __shared__ Smem sm;
    int t = threadIdx.x, lane = t & 63, w = t >> 6;
    int quad = lane >> 4, nl = lane & 15;
    int rowBase = blockIdx.x * GR;

    floatx4 acc[2][8];
    floatx4 zero = {0.f, 0.f, 0.f, 0.f};
#pragma unroll
    for (int a = 0; a < 2; a++)
#pragma unroll
        for (int b = 0; b < 8; b++) acc[a][b] = zero;

    const float*          Xf = (const float*)Xv;
    const unsigned short* Xb = (const unsigned short*)Xv;

    for (int k0 = 0; k0 < K; k0 += KC) {
        // stage X tile (128 rows x 64 k) as bf16
#pragma unroll
        for (int it = 0; it < 4; it++) {
            int s5 = t + it * 256;
            int row = s5 >> 3, kg = s5 & 7;
            int gr = rowBase + row;
            unsigned short tmp[8];
            if (XBF16) {
                uint4 v = make_uint4(0, 0, 0, 0);
                if (gr < N_NODES) v = *(const uint4*)&Xb[(size_t)gr * K + k0 + kg * 8];
                *(uint4*)tmp = v;
            } else {
                float4 v0 = make_float4(0, 0, 0, 0), v1 = v0;
                if (gr < N_NODES) {
                    const float* p = &Xf[(size_t)gr * K + k0 + kg * 8];
                    v0 = *(const float4*)p;
                    v1 = *(const float4*)(p + 4);
                }
                tmp[0] = f2bf(v0.x); tmp[1] = f2bf(v0.y); tmp[2] = f2bf(v0.z); tmp[3] = f2bf(v0.w);
                tmp[4] = f2bf(v1.x); tmp[5] = f2bf(v1.y); tmp[6] = f2bf(v1.z); tmp[7] = f2bf(v1.w);
            }
            *(uint4*)&sm.s.Xs[row][kg * 8] = *(uint4*)tmp;
        }
        // stage Wt tile (128 n x 64 k), already bf16
#pragma unroll
        for (int it = 0; it < 4; it++) {
            int s5 = t + it * 256;
            int n = s5 >> 3, kg = s5 & 7;
            *(uint4*)&sm.s.Ws[n][kg * 8] = *(const uint4*)&Wt[(size_t)n * K + k0 + kg * 8];
        }
        __syncthreads();
#pragma unroll
        for (int ks = 0; ks < 2; ks++) {
            int kb = ks * 32 + quad * 8;
            short8 a0 = *(const short8*)&sm.s.Xs[w * 32 + nl][kb];
            short8 a1 = *(const short8*)&sm.s.Xs[w * 32 + 16 + nl][kb];
#pragma unroll
            for (int ct = 0; ct < 8; ct++) {
                short8 b = *(const short8*)&sm.s.Ws[ct * 16 + nl][kb];
                acc[0][ct] = __builtin_amdgcn_mfma_f32_16x16x32_bf16(a0, b, acc[0][ct], 0, 0, 0);
                acc[1][ct] = __builtin_amdgcn_mfma_f32_16x16x32_bf16(a1, b, acc[1][ct], 0, 0, 0);
            }
        }
        __syncthreads();
    }

    // acc -> Hs (bf16). Wave w writes rows [w*32, w*32+32) only.
#pragma unroll
    for (int rt = 0; rt < 2; rt++)
#pragma unroll
        for (int ct = 0; ct < 8; ct++)
#pragma unroll
            for (int r = 0; r < 4; r++)
                sm.Hs[w * 32 + rt * 16 + quad * 4 + r][ct * 16 + nl] = f2bf(acc[rt][ct][r]);

    // readback: coalesced global store + fused att dots.
    float asv[8], adv[8];
    {
        const float* ap = &att_src[nl * 8];
        const float* dp = &att_dst[nl * 8];
        *(float4*)&asv[0] = *(const float4*)ap;  *(float4*)&asv[4] = *(const float4*)(ap + 4);
        *(float4*)&adv[0] = *(const float4*)dp;  *(float4*)&adv[4] = *(const float4*)(dp + 4);
    }
    int hd = nl >> 2;
#pragma unroll
    for (int it = 0; it < 8; it++) {
        int rl = w * 32 + it * 4 + quad;
        int grow = rowBase + rl;
        uint4 v = *(const uint4*)&sm.Hs[rl][nl * 8];
        float f[8];
        f[0] = __uint_as_float(v.x << 16); f[1] = __uint_as_float(v.x & 0xffff0000u);
        f[2] = __uint_as_float(v.y << 16); f[3] = __uint_as_float(v.y & 0xffff0000u);
        f[4] = __uint_as_float(v.z << 16); f[5] = __uint_as_float(v.z & 0xffff0000u);
        f[6] = __uint_as_float(v.w << 16); f[7] = __uint_as_float(v.w & 0xffff0000u);
        float ds = 0.f, dd = 0.f;
#pragma unroll
        for (int j = 0; j < 8; j++) {
            ds = fmaf(f[j], asv[j], ds);
            dd = fmaf(f[j], adv[j], dd);
        }
        ds += __shfl_xor(ds, 1); ds += __shfl_xor(ds, 2);
        dd += __shfl_xor(dd, 1); dd += __shfl_xor(dd, 2);
        if (grow < N_NODES) {
            *(uint4*)&Hout[(size_t)grow * HID + nl * 8] = v;
            if ((nl & 3) == 0) { aS[grow * 4 + hd] = ds; aD[grow * 4 + hd] = dd; }
        }
    }
}

// ---------------------------------------------------------------------------
// alpha_kernel: one wave per dst node, single pass (deg<=128 cached).
// ---------------------------------------------------------------------------
__global__ __launch_bounds__(256) void alpha_kernel(const float* __restrict__ a_s,
                                                    const float* __restrict__ a_d,
                                                    const int* __restrict__ offsets,
                                                    const int* __restrict__ csr,
                                                    float* __restrict__ alpha) {
    int wid  = (blockIdx.x * blockDim.x + threadIdx.x) >> 6;
    int lane = threadIdx.x & 63;
    if (wid >= N_NODES) return;
    int n = wid;
    int start = offsets[n], end = offsets[n + 1];
    float4 ad4 = *(const float4*)&a_d[n * 4];

    int i0 = start + lane;
    int i1 = i0 + 64;
    bool v0 = i0 < end, v1 = i1 < end;

    float e00 = -1e30f, e01 = -1e30f, e02 = -1e30f, e03 = -1e30f;
    float e10 = -1e30f, e11 = -1e30f, e12 = -1e30f, e13 = -1e30f;
    if (v0) {
        float4 as4 = *(const float4*)&a_s[csr[i0] * 4];
        e00 = as4.x + ad4.x; e00 = e00 > 0.f ? e00 : 0.2f * e00;
        e01 = as4.y + ad4.y; e01 = e01 > 0.f ? e01 : 0.2f * e01;
        e02 = as4.z + ad4.z; e02 = e02 > 0.f ? e02 : 0.2f * e02;
        e03 = as4.w + ad4.w; e03 = e03 > 0.f ? e03 : 0.2f * e03;
    }
    if (v1) {
        float4 as4 = *(const float4*)&a_s[csr[i1] * 4];
        e10 = as4.x + ad4.x; e10 = e10 > 0.f ? e10 : 0.2f * e10;
        e11 = as4.y + ad4.y; e11 = e11 > 0.f ? e11 : 0.2f * e11;
        e12 = as4.z + ad4.z; e12 = e12 > 0.f ? e12 : 0.2f * e12;
        e13 = as4.w + ad4.w; e13 = e13 > 0.f ? e13 : 0.2f * e13;
    }
    float m0 = fmaxf(e00, e10), m1 = fmaxf(e01, e11);
    float m2 = fmaxf(e02, e12), m3 = fmaxf(e03, e13);
    for (int i = start + 128 + lane; i < end; i += 64) {
        float4 as4 = *(const float4*)&a_s[csr[i] * 4];
        float f0 = as4.x + ad4.x; f0 = f0 > 0.f ? f0 : 0.2f * f0;
        float f1 = as4.y + ad4.y; f1 = f1 > 0.f ? f1 : 0.2f * f1;
        float f2 = as4.z + ad4.z; f2 = f2 > 0.f ? f2 : 0.2f * f2;
        float f3 = as4.w + ad4.w; f3 = f3 > 0.f ? f3 : 0.2f * f3;
        m0 = fmaxf(m0, f0); m1 = fmaxf(m1, f1);
        m2 = fmaxf(m2, f2); m3 = fmaxf(m3, f3);
    }
#pragma unroll
    for (int off = 32; off > 0; off >>= 1) {
        m0 = fmaxf(m0, __shfl_xor(m0, off));
        m1 = fmaxf(m1, __shfl_xor(m1, off));
        m2 = fmaxf(m2, __shfl_xor(m2, off));
        m3 = fmaxf(m3, __shfl_xor(m3, off));
    }

    float x00 = __expf(e00 - m0), x01 = __expf(e01 - m1);
    float x02 = __expf(e02 - m2), x03 = __expf(e03 - m3);
    float x10 = __expf(e10 - m0), x11 = __expf(e11 - m1);
    float x12 = __expf(e12 - m2), x13 = __expf(e13 - m3);
    float d0 = x00 + x10, d1 = x01 + x11, d2 = x02 + x12, d3 = x03 + x13;
    for (int i = start + 128 + lane; i < end; i += 64) {
        float4 as4 = *(const float4*)&a_s[csr[i] * 4];
        float f0 = as4.x + ad4.x; f0 = f0 > 0.f ? f0 : 0.2f * f0;
        float f1 = as4.y + ad4.y; f1 = f1 > 0.f ? f1 : 0.2f * f1;
        float f2 = as4.z + ad4.z; f2 = f2 > 0.f ? f2 : 0.2f * f2;
        float f3 = as4.w + ad4.w; f3 = f3 > 0.f ? f3 : 0.2f * f3;
        d0 += __expf(f0 - m0); d1 += __expf(f1 - m1);
        d2 += __expf(f2 - m2); d3 += __expf(f3 - m3);
    }
#pragma unroll
    for (int off = 32; off > 0; off >>= 1) {
        d0 += __shfl_xor(d0, off);
        d1 += __shfl_xor(d1, off);
        d2 += __shfl_xor(d2, off);
        d3 += __shfl_xor(d3, off);
    }
    float rd0 = 1.0f / (d0 + 1e-16f);
    float rd1 = 1.0f / (d1 + 1e-16f);
    float rd2 = 1.0f / (d2 + 1e-16f);
    float rd3 = 1.0f / (d3 + 1e-16f);

    if (v0) {
        float4 al; al.x = x00 * rd0; al.y = x01 * rd1; al.z = x02 * rd2; al.w = x03 * rd3;
        *(float4*)&alpha[(size_t)i0 * 4] = al;
    }
    if (v1) {
        float4 al; al.x = x10 * rd0; al.y = x11 * rd1; al.z = x12 * rd2; al.w = x13 * rd3;
        *(float4*)&alpha[(size_t)i1 * 4] = al;
    }
    for (int i = start + 128 + lane; i < end; i += 64) {
        float4 as4 = *(const float4*)&a_s[csr[i] * 4];
        float f0 = as4.x + ad4.x; f0 = f0 > 0.f ? f0 : 0.2f * f0;
        float f1 = as4.y + ad4.y; f1 = f1 > 0.f ? f1 : 0.2f * f1;
        float f2 = as4.z + ad4.z; f2 = f2 > 0.f ? f2 : 0.2f * f2;
        float f3 = as4.w + ad4.w; f3 = f3 > 0.f ? f3 : 0.2f * f3;
        float4 al;
        al.x = __expf(f0 - m0) * rd0; al.y = __expf(f1 - m1) * rd1;
        al.z = __expf(f2 - m2) * rd2; al.w = __expf(f3 - m3) * rd3;
        *(float4*)&alpha[(size_t)i * 4] = al;
    }
}

// ---------------------------------------------------------------------------
// agg_kernel: one wave per dst node; lane covers channels {2*lane, 2*lane+1}
// (same head), h in bf16 (uint = 2 ch). Unroll 8 for MLP. Fused BN+ReLU.
// ---------------------------------------------------------------------------
template<bool OUTBF16>
__global__ __launch_bounds__(256) void agg_kernel(const unsigned short* __restrict__ hfeat,
                                                  const float* __restrict__ alpha,
                                                  const int* __restrict__ offsets,
                                                  const int* __restrict__ csr,
                                                  const float* __restrict__ coefA,
                                                  const float* __restrict__ coefB,
                                                  void* __restrict__ outv) {
    int n    = (blockIdx.x * blockDim.x + threadIdx.x) >> 6;
    int lane = threadIdx.x & 63;
    if (n >= N_NODES) return;
    int c  = lane * 2;
    int h0 = lane >> 4;            // head of both channels
    int start = offsets[n], end = offsets[n + 1];

    float acc0 = 0.f, acc1 = 0.f;
    int i = start;
    for (; i + 7 < end; i += 8) {
        int sA[8]; float aA[8]; unsigned int vA[8];
#pragma unroll
        for (int j = 0; j < 8; j++) sA[j] = csr[i + j];
#pragma unroll
        for (int j = 0; j < 8; j++) aA[j] = alpha[(size_t)(i + j) * 4 + h0];
#pragma unroll
        for (int j = 0; j < 8; j++) vA[j] = *(const unsigned int*)&hfeat[(size_t)sA[j] * HID + c];
#pragma unroll
        for (int j = 0; j < 8; j++) {
            acc0 = fmaf(__uint_as_float(vA[j] << 16),          aA[j], acc0);
            acc1 = fmaf(__uint_as_float(vA[j] & 0xffff0000u),  aA[j], acc1);
        }
    }
    for (; i < end; i++) {
        int s = csr[i];
        float al = alpha[(size_t)i * 4 + h0];
        unsigned int v = *(const unsigned int*)&hfeat[(size_t)s * HID + c];
        acc0 = fmaf(__uint_as_float(v << 16),         al, acc0);
        acc1 = fmaf(__uint_as_float(v & 0xffff0000u), al, acc1);
    }
    float2 cA = *(const float2*)&coefA[c];
    float2 cB = *(const float2*)&coefB[c];
    float o0 = fmaxf(fmaf(acc0, cA.x, cB.x), 0.f);
    float o1 = fmaxf(fmaf(acc1, cA.y, cB.y), 0.f);
    if (OUTBF16) {
        unsigned int pk = (unsigned int)f2bf(o0) | ((unsigned int)f2bf(o1) << 16);
        ((unsigned int*)outv)[(size_t)n * 64 + lane] = pk;
    } else {
        ((float2*)outv)[(size_t)n * 64 + lane] = make_float2(o0, o1);
    }
}

// ---------------------------------------------------------------------------
extern "C" void kernel_launch(void* const* d_in, const int* in_sizes, int n_in,
                              void* d_out, int out_size, void* d_ws, size_t ws_size,
                              hipStream_t stream) {
    const float* x    = (const float*)d_in[0];
    const int*   ei   = (const int*)d_in[1];
    const float* W1   = (const float*)d_in[2];
    const float* as1  = (const float*)d_in[3];
    const float* ad1  = (const float*)d_in[4];
    const float* b1   = (const float*)d_in[5];
    const float* g1   = (const float*)d_in[6];
    const float* be1  = (const float*)d_in[7];
    const float* mn1  = (const float*)d_in[8];
    const float* vr1  = (const float*)d_in[9];
    const float* W2   = (const float*)d_in[10];
    const float* as2  = (const float*)d_in[11];
    const float* ad2  = (const float*)d_in[12];
    const float* b2   = (const float*)d_in[13];
    const float* g2   = (const float*)d_in[14];
    const float* be2  = (const float*)d_in[15];
    const float* mn2  = (const float*)d_in[16];
    const float* vr2  = (const float*)d_in[17];
    float* out = (float*)d_out;

    unsigned short* hb  = (unsigned short*)d_ws;                  // N*128 bf16
    unsigned short* x2b = hb + (size_t)N_NODES * HID;             // N*128 bf16
    unsigned short* Wt1 = x2b + (size_t)N_NODES * HID;            // 128*256
    unsigned short* Wt2 = Wt1 + 128 * 256;                        // 128*128
    float* aS    = (float*)(Wt2 + 128 * 128);                     // N*4
    float* aD    = aS + N_NODES * NH;                             // N*4
    float* alpha = aD + N_NODES * NH;                             // ETOT*4
    float* coef  = alpha + (size_t)ETOT * 4;                      // 512
    int* counts    = (int*)(coef + 512);                          // N
    int* offsets   = counts + N_NODES;                            // N+1
    int* cursor    = offsets + N_NODES + 1;                       // N
    int* blockSums = cursor + N_NODES;                            // 256
    int* csr       = blockSums + 256;                             // ETOT

    hipMemsetAsync(counts, 0, N_NODES * sizeof(int), stream);
    count_kernel<<<(ETOT + 255) / 256, 256, 0, stream>>>(ei, counts);
    scan1_kernel<<<SCAN_B, 256, 0, stream>>>(counts, offsets, blockSums);
    scan2_kernel<<<1, 256, 0, stream>>>(blockSums);
    scan3_kernel<<<SCAN_B, 256, 0, stream>>>(offsets, blockSums, cursor);
    scatter_kernel<<<(ETOT + 255) / 256, 256, 0, stream>>>(ei, cursor, csr);
    coef_kernel<<<1, 256, 0, stream>>>(b1, g1, be1, mn1, vr1, b2, g2, be2, mn2, vr2, coef);
    wtrans_kernel<<<128, 256, 0, stream>>>(W1, W2, Wt1, Wt2);

    int gemmGrid = (N_NODES + GR - 1) / GR;   // 391
    int nodeGrid = (N_NODES + 3) / 4;         // 12500 (1 wave/node)

    // Layer 1
    gemm_att_kernel<false><<<gemmGrid, 256, 0, stream>>>(x, Wt1, as1, ad1, hb, aS, aD, 256);
    alpha_kernel<<<nodeGrid, 256, 0, stream>>>(aS, aD, offsets, csr, alpha);
    agg_kernel<true><<<nodeGrid, 256, 0, stream>>>(hb, alpha, offsets, csr,
                                                   coef, coef + 128, (void*)x2b);
    // Layer 2
    gemm_att_kernel<true><<<gemmGrid, 256, 0, stream>>>(x2b, Wt2, as2, ad2, hb, aS, aD, 128);
    alpha_kernel<<<nodeGrid, 256, 0, stream>>>(aS, aD, offsets, csr, alpha);
    agg_kernel<false><<<nodeGrid, 256, 0, stream>>>(hb, alpha, offsets, csr,
                                                    coef + 256, coef + 384, (void*)out);
}

// Round 5
// 343.437 us; speedup vs baseline: 2.0715x; 1.1291x over previous
//
#include <hip/hip_runtime.h>
#include <math.h>

#define N_NODES 50000
#define EDGES   800000
#define ETOT    (EDGES + N_NODES)
#define HID     128
#define NH      4

typedef __attribute__((ext_vector_type(8))) short short8;
typedef __attribute__((ext_vector_type(4))) float floatx4;

__device__ inline unsigned short f2bf(float f) {
    unsigned int u = __float_as_uint(f);
    u = u + 0x7FFFu + ((u >> 16) & 1u);   // RNE
    return (unsigned short)(u >> 16);
}

__device__ inline float sel4(float4 v, int h) {
    return h == 0 ? v.x : (h == 1 ? v.y : (h == 2 ? v.z : v.w));
}

// ---------------------------------------------------------------------------
// CSR build: counts -> hierarchical exclusive scan -> scatter
// 4 edges/thread for memory-level parallelism on the atomic chains.
// ---------------------------------------------------------------------------
__global__ void count_kernel(const int* __restrict__ ei, int* __restrict__ counts) {
    int i4 = (blockIdx.x * blockDim.x + threadIdx.x) * 4;
    if (i4 >= ETOT) return;
    if (i4 < EDGES) {   // EDGES % 4 == 0: whole quad in edge region
        int4 dv = *(const int4*)&ei[EDGES + i4];
        atomicAdd(&counts[dv.x], 1);
        atomicAdd(&counts[dv.y], 1);
        atomicAdd(&counts[dv.z], 1);
        atomicAdd(&counts[dv.w], 1);
    } else {            // self-loop quad
        int b = i4 - EDGES;
        atomicAdd(&counts[b], 1);
        atomicAdd(&counts[b + 1], 1);
        atomicAdd(&counts[b + 2], 1);
        atomicAdd(&counts[b + 3], 1);
    }
}

#define SCAN_B ((N_NODES + 255) / 256)   // 196 blocks of 256
__global__ __launch_bounds__(256) void scan1_kernel(const int* __restrict__ counts,
                                                    int* __restrict__ offsets,
                                                    int* __restrict__ blockSums) {
    __shared__ int sh[256];
    int t = threadIdx.x;
    int g = blockIdx.x * 256 + t;
    int v = (g < N_NODES) ? counts[g] : 0;
    sh[t] = v;
    __syncthreads();
    for (int off = 1; off < 256; off <<= 1) {
        int x = sh[t];
        int add = (t >= off) ? sh[t - off] : 0;
        __syncthreads();
        sh[t] = x + add;
        __syncthreads();
    }
    if (g < N_NODES) offsets[g] = sh[t] - v;
    if (t == 255) blockSums[blockIdx.x] = sh[255];
}

__global__ __launch_bounds__(256) void scan2_kernel(int* __restrict__ blockSums) {
    __shared__ int sh[256];
    int t = threadIdx.x;
    int v = (t < SCAN_B) ? blockSums[t] : 0;
    sh[t] = v;
    __syncthreads();
    for (int off = 1; off < 256; off <<= 1) {
        int x = sh[t];
        int add = (t >= off) ? sh[t - off] : 0;
        __syncthreads();
        sh[t] = x + add;
        __syncthreads();
    }
    if (t < SCAN_B) blockSums[t] = sh[t] - v;
}

__global__ __launch_bounds__(256) void scan3_kernel(int* __restrict__ offsets,
                                                    const int* __restrict__ blockSums,
                                                    int* __restrict__ cursor) {
    int g = blockIdx.x * 256 + threadIdx.x;
    if (g < N_NODES) {
        int off = offsets[g] + blockSums[blockIdx.x];
        offsets[g] = off;
        cursor[g] = off;
    }
    if (g == 0) offsets[N_NODES] = ETOT;
}

__global__ void scatter_kernel(const int* __restrict__ ei, int* __restrict__ cursor,
                               int* __restrict__ csr) {
    int i4 = (blockIdx.x * blockDim.x + threadIdx.x) * 4;
    if (i4 >= ETOT) return;
    int s[4], d[4];
    if (i4 < EDGES) {
        int4 sv = *(const int4*)&ei[i4];
        int4 dv = *(const int4*)&ei[EDGES + i4];
        s[0] = sv.x; s[1] = sv.y; s[2] = sv.z; s[3] = sv.w;
        d[0] = dv.x; d[1] = dv.y; d[2] = dv.z; d[3] = dv.w;
    } else {
        int b = i4 - EDGES;
#pragma unroll
        for (int j = 0; j < 4; j++) { s[j] = b + j; d[j] = b + j; }
    }
    int p[4];
#pragma unroll
    for (int j = 0; j < 4; j++) p[j] = atomicAdd(&cursor[d[j]], 1);
#pragma unroll
    for (int j = 0; j < 4; j++) csr[p[j]] = s[j];
}

// ---------------------------------------------------------------------------
// coef: fold bias+BN into per-channel affine. [A1|B1|A2|B2] (128 each)
// ---------------------------------------------------------------------------
__global__ void coef_kernel(const float* __restrict__ b1, const float* __restrict__ g1,
                            const float* __restrict__ be1, const float* __restrict__ mn1,
                            const float* __restrict__ vr1,
                            const float* __restrict__ b2, const float* __restrict__ g2,
                            const float* __restrict__ be2, const float* __restrict__ mn2,
                            const float* __restrict__ vr2, float* __restrict__ coef) {
    int t = threadIdx.x;
    if (t < 128) {
        float sc = g1[t] * rsqrtf(vr1[t] + 1e-5f);
        coef[t]       = sc;
        coef[128 + t] = be1[t] + (b1[t] - mn1[t]) * sc;
    } else {
        int c = t - 128;
        float sc = g2[c] * rsqrtf(vr2[c] + 1e-5f);
        coef[256 + c] = sc;
        coef[384 + c] = be2[c] + (b2[c] - mn2[c]) * sc;
    }
}

// ---------------------------------------------------------------------------
// W transpose + bf16 convert: Wt[n][k] = bf16(W[k][n])
// ---------------------------------------------------------------------------
__global__ void wtrans_kernel(const float* __restrict__ W1, const float* __restrict__ W2,
                              unsigned short* __restrict__ Wt1, unsigned short* __restrict__ Wt2) {
    int i = blockIdx.x * 256 + threadIdx.x;
    if (i < 256 * 128) { int k = i >> 7, n = i & 127; Wt1[(size_t)n * 256 + k] = f2bf(W1[i]); }
    if (i < 128 * 128) { int k = i >> 7, n = i & 127; Wt2[(size_t)n * 128 + k] = f2bf(W2[i]); }
}

// ---------------------------------------------------------------------------
// MFMA GEMM (bf16 in, fp32 acc) + fused attention dots + bf16 H output.
// (unchanged from round 4 — not the bottleneck)
// ---------------------------------------------------------------------------
#define GR   128
#define KC   64
#define PADK 88
#define PADH 136

union Smem {
    struct { unsigned short Xs[GR][PADK]; unsigned short Ws[HID][PADK]; } s;
    unsigned short Hs[GR][PADH];
};

template<bool XBF16>
__global__ __launch_bounds__(256) void gemm_att_kernel(const void* __restrict__ Xv,
                                                       const unsigned short* __restrict__ Wt,
                                                       const float* __restrict__ att_src,
                                                       const float* __restrict__ att_dst,
                                                       unsigned short* __restrict__ Hout,
                                                       float* __restrict__ aS,
                                                       float* __restrict__ aD, int K) {
    __shared__ Smem sm;
    int t = threadIdx.x, lane = t & 63, w = t >> 6;
    int quad = lane >> 4, nl = lane & 15;
    int rowBase = blockIdx.x * GR;

    floatx4 acc[2][8];
    floatx4 zero = {0.f, 0.f, 0.f, 0.f};
#pragma unroll
    for (int a = 0; a < 2; a++)
#pragma unroll
        for (int b = 0; b < 8; b++) acc[a][b] = zero;

    const float*          Xf = (const float*)Xv;
    const unsigned short* Xb = (const unsigned short*)Xv;

    for (int k0 = 0; k0 < K; k0 += KC) {
#pragma unroll
        for (int it = 0; it < 4; it++) {
            int s5 = t + it * 256;
            int row = s5 >> 3, kg = s5 & 7;
            int gr = rowBase + row;
            unsigned short tmp[8];
            if (XBF16) {
                uint4 v = make_uint4(0, 0, 0, 0);
                if (gr < N_NODES) v = *(const uint4*)&Xb[(size_t)gr * K + k0 + kg * 8];
                *(uint4*)tmp = v;
            } else {
                float4 v0 = make_float4(0, 0, 0, 0), v1 = v0;
                if (gr < N_NODES) {
                    const float* p = &Xf[(size_t)gr * K + k0 + kg * 8];
                    v0 = *(const float4*)p;
                    v1 = *(const float4*)(p + 4);
                }
                tmp[0] = f2bf(v0.x); tmp[1] = f2bf(v0.y); tmp[2] = f2bf(v0.z); tmp[3] = f2bf(v0.w);
                tmp[4] = f2bf(v1.x); tmp[5] = f2bf(v1.y); tmp[6] = f2bf(v1.z); tmp[7] = f2bf(v1.w);
            }
            *(uint4*)&sm.s.Xs[row][kg * 8] = *(uint4*)tmp;
        }
#pragma unroll
        for (int it = 0; it < 4; it++) {
            int s5 = t + it * 256;
            int n = s5 >> 3, kg = s5 & 7;
            *(uint4*)&sm.s.Ws[n][kg * 8] = *(const uint4*)&Wt[(size_t)n * K + k0 + kg * 8];
        }
        __syncthreads();
#pragma unroll
        for (int ks = 0; ks < 2; ks++) {
            int kb = ks * 32 + quad * 8;
            short8 a0 = *(const short8*)&sm.s.Xs[w * 32 + nl][kb];
            short8 a1 = *(const short8*)&sm.s.Xs[w * 32 + 16 + nl][kb];
#pragma unroll
            for (int ct = 0; ct < 8; ct++) {
                short8 b = *(const short8*)&sm.s.Ws[ct * 16 + nl][kb];
                acc[0][ct] = __builtin_amdgcn_mfma_f32_16x16x32_bf16(a0, b, acc[0][ct], 0, 0, 0);
                acc[1][ct] = __builtin_amdgcn_mfma_f32_16x16x32_bf16(a1, b, acc[1][ct], 0, 0, 0);
            }
        }
        __syncthreads();
    }

#pragma unroll
    for (int rt = 0; rt < 2; rt++)
#pragma unroll
        for (int ct = 0; ct < 8; ct++)
#pragma unroll
            for (int r = 0; r < 4; r++)
                sm.Hs[w * 32 + rt * 16 + quad * 4 + r][ct * 16 + nl] = f2bf(acc[rt][ct][r]);

    float asv[8], adv[8];
    {
        const float* ap = &att_src[nl * 8];
        const float* dp = &att_dst[nl * 8];
        *(float4*)&asv[0] = *(const float4*)ap;  *(float4*)&asv[4] = *(const float4*)(ap + 4);
        *(float4*)&adv[0] = *(const float4*)dp;  *(float4*)&adv[4] = *(const float4*)(dp + 4);
    }
    int hd = nl >> 2;
#pragma unroll
    for (int it = 0; it < 8; it++) {
        int rl = w * 32 + it * 4 + quad;
        int grow = rowBase + rl;
        uint4 v = *(const uint4*)&sm.Hs[rl][nl * 8];
        float f[8];
        f[0] = __uint_as_float(v.x << 16); f[1] = __uint_as_float(v.x & 0xffff0000u);
        f[2] = __uint_as_float(v.y << 16); f[3] = __uint_as_float(v.y & 0xffff0000u);
        f[4] = __uint_as_float(v.z << 16); f[5] = __uint_as_float(v.z & 0xffff0000u);
        f[6] = __uint_as_float(v.w << 16); f[7] = __uint_as_float(v.w & 0xffff0000u);
        float ds = 0.f, dd = 0.f;
#pragma unroll
        for (int j = 0; j < 8; j++) {
            ds = fmaf(f[j], asv[j], ds);
            dd = fmaf(f[j], adv[j], dd);
        }
        ds += __shfl_xor(ds, 1); ds += __shfl_xor(ds, 2);
        dd += __shfl_xor(dd, 1); dd += __shfl_xor(dd, 2);
        if (grow < N_NODES) {
            *(uint4*)&Hout[(size_t)grow * HID + nl * 8] = v;
            if ((nl & 3) == 0) { aS[grow * 4 + hd] = ds; aD[grow * 4 + hd] = dd; }
        }
    }
}

// ---------------------------------------------------------------------------
// Fused softmax + aggregate: one wave per node (grid exactly N_NODES waves).
// Phase A (lanes over edges): online softmax, alpha+src parked in LDS.
// Phase B (lanes over channels): weighted gather of bf16 h rows.
// deg>128 handled by on-the-fly alpha recompute (wave-uniform m/rd).
// ---------------------------------------------------------------------------
template<bool OUTBF16>
__global__ __launch_bounds__(256) void gather_kernel(const unsigned short* __restrict__ hfeat,
                                                     const float* __restrict__ a_s,
                                                     const float* __restrict__ a_d,
                                                     const int* __restrict__ offsets,
                                                     const int* __restrict__ csr,
                                                     const float* __restrict__ coefA,
                                                     const float* __restrict__ coefB,
                                                     void* __restrict__ outv) {
    __shared__ float alphaS[4][128][4];   // 8 KB
    __shared__ int   srcS[4][128];        // 2 KB
    int t = threadIdx.x, lane = t & 63, ws = t >> 6;
    int n = blockIdx.x * 4 + ws;          // 12500 blocks * 4 waves == N_NODES
    int start = offsets[n], end = offsets[n + 1];
    int deg = end - start;
    float4 ad4 = *(const float4*)&a_d[n * 4];

    // ---- Phase A: softmax over incoming edges ----
    int i0 = start + lane, i1 = i0 + 64;
    bool v0 = lane < deg, v1 = lane + 64 < deg;
    int s0 = 0, s1 = 0;
    float e00 = -1e30f, e01 = -1e30f, e02 = -1e30f, e03 = -1e30f;
    float e10 = -1e30f, e11 = -1e30f, e12 = -1e30f, e13 = -1e30f;
    if (v0) {
        s0 = csr[i0];
        float4 as4 = *(const float4*)&a_s[s0 * 4];
        e00 = as4.x + ad4.x; e00 = e00 > 0.f ? e00 : 0.2f * e00;
        e01 = as4.y + ad4.y; e01 = e01 > 0.f ? e01 : 0.2f * e01;
        e02 = as4.z + ad4.z; e02 = e02 > 0.f ? e02 : 0.2f * e02;
        e03 = as4.w + ad4.w; e03 = e03 > 0.f ? e03 : 0.2f * e03;
    }
    if (v1) {
        s1 = csr[i1];
        float4 as4 = *(const float4*)&a_s[s1 * 4];
        e10 = as4.x + ad4.x; e10 = e10 > 0.f ? e10 : 0.2f * e10;
        e11 = as4.y + ad4.y; e11 = e11 > 0.f ? e11 : 0.2f * e11;
        e12 = as4.z + ad4.z; e12 = e12 > 0.f ? e12 : 0.2f * e12;
        e13 = as4.w + ad4.w; e13 = e13 > 0.f ? e13 : 0.2f * e13;
    }
    float m0 = fmaxf(e00, e10), m1 = fmaxf(e01, e11);
    float m2 = fmaxf(e02, e12), m3 = fmaxf(e03, e13);
    for (int i = start + 128 + lane; i < end; i += 64) {   // rare
        float4 as4 = *(const float4*)&a_s[csr[i] * 4];
        float f0 = as4.x + ad4.x; f0 = f0 > 0.f ? f0 : 0.2f * f0;
        float f1 = as4.y + ad4.y; f1 = f1 > 0.f ? f1 : 0.2f * f1;
        float f2 = as4.z + ad4.z; f2 = f2 > 0.f ? f2 : 0.2f * f2;
        float f3 = as4.w + ad4.w; f3 = f3 > 0.f ? f3 : 0.2f * f3;
        m0 = fmaxf(m0, f0); m1 = fmaxf(m1, f1);
        m2 = fmaxf(m2, f2); m3 = fmaxf(m3, f3);
    }
#pragma unroll
    for (int off = 32; off > 0; off >>= 1) {
        m0 = fmaxf(m0, __shfl_xor(m0, off));
        m1 = fmaxf(m1, __shfl_xor(m1, off));
        m2 = fmaxf(m2, __shfl_xor(m2, off));
        m3 = fmaxf(m3, __shfl_xor(m3, off));
    }
    float x00 = __expf(e00 - m0), x01 = __expf(e01 - m1);
    float x02 = __expf(e02 - m2), x03 = __expf(e03 - m3);
    float x10 = __expf(e10 - m0), x11 = __expf(e11 - m1);
    float x12 = __expf(e12 - m2), x13 = __expf(e13 - m3);
    float d0 = x00 + x10, d1 = x01 + x11, d2 = x02 + x12, d3 = x03 + x13;
    for (int i = start + 128 + lane; i < end; i += 64) {   // rare
        float4 as4 = *(const float4*)&a_s[csr[i] * 4];
        float f0 = as4.x + ad4.x; f0 = f0 > 0.f ? f0 : 0.2f * f0;
        float f1 = as4.y + ad4.y; f1 = f1 > 0.f ? f1 : 0.2f * f1;
        float f2 = as4.z + ad4.z; f2 = f2 > 0.f ? f2 : 0.2f * f2;
        float f3 = as4.w + ad4.w; f3 = f3 > 0.f ? f3 : 0.2f * f3;
        d0 += __expf(f0 - m0); d1 += __expf(f1 - m1);
        d2 += __expf(f2 - m2); d3 += __expf(f3 - m3);
    }
#pragma unroll
    for (int off = 32; off > 0; off >>= 1) {
        d0 += __shfl_xor(d0, off);
        d1 += __shfl_xor(d1, off);
        d2 += __shfl_xor(d2, off);
        d3 += __shfl_xor(d3, off);
    }
    float rd0 = 1.0f / (d0 + 1e-16f);
    float rd1 = 1.0f / (d1 + 1e-16f);
    float rd2 = 1.0f / (d2 + 1e-16f);
    float rd3 = 1.0f / (d3 + 1e-16f);

    if (v0) {
        float4 al; al.x = x00 * rd0; al.y = x01 * rd1; al.z = x02 * rd2; al.w = x03 * rd3;
        *(float4*)&alphaS[ws][lane][0] = al;
        srcS[ws][lane] = s0;
    }
    if (v1) {
        float4 al; al.x = x10 * rd0; al.y = x11 * rd1; al.z = x12 * rd2; al.w = x13 * rd3;
        *(float4*)&alphaS[ws][lane + 64][0] = al;
        srcS[ws][lane + 64] = s1;
    }
    __syncthreads();

    // ---- Phase B: weighted gather ----
    int c = lane * 2;
    int h0 = lane >> 4;
    float mh  = sel4(make_float4(m0, m1, m2, m3), h0);
    float rdh = sel4(make_float4(rd0, rd1, rd2, rd3), h0);
    float adh = sel4(ad4, h0);

    float acc0 = 0.f, acc1 = 0.f;
    int cap = deg < 128 ? deg : 128;
    int j = 0;
    for (; j + 3 < cap; j += 4) {
        int sA = srcS[ws][j], sB = srcS[ws][j + 1], sC = srcS[ws][j + 2], sD = srcS[ws][j + 3];
        float aA = alphaS[ws][j][h0],     aB = alphaS[ws][j + 1][h0];
        float aC = alphaS[ws][j + 2][h0], aD2 = alphaS[ws][j + 3][h0];
        unsigned int vA = *(const unsigned int*)&hfeat[(size_t)sA * HID + c];
        unsigned int vB = *(const unsigned int*)&hfeat[(size_t)sB * HID + c];
        unsigned int vC = *(const unsigned int*)&hfeat[(size_t)sC * HID + c];
        unsigned int vD = *(const unsigned int*)&hfeat[(size_t)sD * HID + c];
        acc0 = fmaf(__uint_as_float(vA << 16),         aA,  acc0);
        acc1 = fmaf(__uint_as_float(vA & 0xffff0000u), aA,  acc1);
        acc0 = fmaf(__uint_as_float(vB << 16),         aB,  acc0);
        acc1 = fmaf(__uint_as_float(vB & 0xffff0000u), aB,  acc1);
        acc0 = fmaf(__uint_as_float(vC << 16),         aC,  acc0);
        acc1 = fmaf(__uint_as_float(vC & 0xffff0000u), aC,  acc1);
        acc0 = fmaf(__uint_as_float(vD << 16),         aD2, acc0);
        acc1 = fmaf(__uint_as_float(vD & 0xffff0000u), aD2, acc1);
    }
    for (; j < cap; j++) {
        int s = srcS[ws][j];
        float al = alphaS[ws][j][h0];
        unsigned int v = *(const unsigned int*)&hfeat[(size_t)s * HID + c];
        acc0 = fmaf(__uint_as_float(v << 16),         al, acc0);
        acc1 = fmaf(__uint_as_float(v & 0xffff0000u), al, acc1);
    }
    for (; j < deg; j++) {   // rare: recompute alpha on the fly
        int s = csr[start + j];
        float as = a_s[s * 4 + h0];
        float e = as + adh; e = e > 0.f ? e : 0.2f * e;
        float al = __expf(e - mh) * rdh;
        unsigned int v = *(const unsigned int*)&hfeat[(size_t)s * HID + c];
        acc0 = fmaf(__uint_as_float(v << 16),         al, acc0);
        acc1 = fmaf(__uint_as_float(v & 0xffff0000u), al, acc1);
    }
    float2 cA = *(const float2*)&coefA[c];
    float2 cB = *(const float2*)&coefB[c];
    float o0 = fmaxf(fmaf(acc0, cA.x, cB.x), 0.f);
    float o1 = fmaxf(fmaf(acc1, cA.y, cB.y), 0.f);
    if (OUTBF16) {
        unsigned int pk = (unsigned int)f2bf(o0) | ((unsigned int)f2bf(o1) << 16);
        ((unsigned int*)outv)[(size_t)n * 64 + lane] = pk;
    } else {
        ((float2*)outv)[(size_t)n * 64 + lane] = make_float2(o0, o1);
    }
}

// ---------------------------------------------------------------------------
extern "C" void kernel_launch(void* const* d_in, const int* in_sizes, int n_in,
                              void* d_out, int out_size, void* d_ws, size_t ws_size,
                              hipStream_t stream) {
    const float* x    = (const float*)d_in[0];
    const int*   ei   = (const int*)d_in[1];
    const float* W1   = (const float*)d_in[2];
    const float* as1  = (const float*)d_in[3];
    const float* ad1  = (const float*)d_in[4];
    const float* b1   = (const float*)d_in[5];
    const float* g1   = (const float*)d_in[6];
    const float* be1  = (const float*)d_in[7];
    const float* mn1  = (const float*)d_in[8];
    const float* vr1  = (const float*)d_in[9];
    const float* W2   = (const float*)d_in[10];
    const float* as2  = (const float*)d_in[11];
    const float* ad2  = (const float*)d_in[12];
    const float* b2   = (const float*)d_in[13];
    const float* g2   = (const float*)d_in[14];
    const float* be2  = (const float*)d_in[15];
    const float* mn2  = (const float*)d_in[16];
    const float* vr2  = (const float*)d_in[17];
    float* out = (float*)d_out;

    unsigned short* hb  = (unsigned short*)d_ws;                  // N*128 bf16
    unsigned short* x2b = hb + (size_t)N_NODES * HID;             // N*128 bf16
    unsigned short* Wt1 = x2b + (size_t)N_NODES * HID;            // 128*256
    unsigned short* Wt2 = Wt1 + 128 * 256;                        // 128*128
    float* aS    = (float*)(Wt2 + 128 * 128);                     // N*4
    float* aD    = aS + N_NODES * NH;                             // N*4
    float* coef  = aD + N_NODES * NH;                             // 512
    int* counts    = (int*)(coef + 512);                          // N
    int* offsets   = counts + N_NODES;                            // N+1
    int* cursor    = offsets + N_NODES + 1;                       // N
    int* blockSums = cursor + N_NODES;                            // 256
    int* csr       = blockSums + 256;                             // ETOT

    hipMemsetAsync(counts, 0, N_NODES * sizeof(int), stream);
    int quadGrid = (ETOT / 4 + 255) / 256;   // 831
    count_kernel<<<quadGrid, 256, 0, stream>>>(ei, counts);
    scan1_kernel<<<SCAN_B, 256, 0, stream>>>(counts, offsets, blockSums);
    scan2_kernel<<<1, 256, 0, stream>>>(blockSums);
    scan3_kernel<<<SCAN_B, 256, 0, stream>>>(offsets, blockSums, cursor);
    scatter_kernel<<<quadGrid, 256, 0, stream>>>(ei, cursor, csr);
    coef_kernel<<<1, 256, 0, stream>>>(b1, g1, be1, mn1, vr1, b2, g2, be2, mn2, vr2, coef);
    wtrans_kernel<<<128, 256, 0, stream>>>(W1, W2, Wt1, Wt2);

    int gemmGrid = (N_NODES + GR - 1) / GR;   // 391
    int nodeGrid = N_NODES / 4;               // 12500, exact (4 waves/block)

    // Layer 1
    gemm_att_kernel<false><<<gemmGrid, 256, 0, stream>>>(x, Wt1, as1, ad1, hb, aS, aD, 256);
    gather_kernel<true><<<nodeGrid, 256, 0, stream>>>(hb, aS, aD, offsets, csr,
                                                      coef, coef + 128, (void*)x2b);
    // Layer 2
    gemm_att_kernel<true><<<gemmGrid, 256, 0, stream>>>(x2b, Wt2, as2, ad2, hb, aS, aD, 128);
    gather_kernel<false><<<nodeGrid, 256, 0, stream>>>(hb, aS, aD, offsets, csr,
                                                       coef + 256, coef + 384, (void*)out);
}

// Round 6
// 287.276 us; speedup vs baseline: 2.4765x; 1.1955x over previous
//
#include <hip/hip_runtime.h>
#include <math.h>

#define N_NODES 50000
#define EDGES   800000
#define ETOT    (EDGES + N_NODES)
#define HID     128
#define NH      4

typedef __attribute__((ext_vector_type(8))) short short8;
typedef __attribute__((ext_vector_type(4))) float floatx4;

__device__ inline unsigned short f2bf(float f) {
    unsigned int u = __float_as_uint(f);
    u = u + 0x7FFFu + ((u >> 16) & 1u);   // RNE
    return (unsigned short)(u >> 16);
}

__device__ inline float sel4(float4 v, int h) {
    return h == 0 ? v.x : (h == 1 ? v.y : (h == 2 ? v.z : v.w));
}

// ---------------------------------------------------------------------------
// CSR build via radix binning by dst (line-dense writes, no 16x amplification)
// Buckets of 128 nodes: NB = ceil(50000/128) = 391.
// ---------------------------------------------------------------------------
#define NB 391
#define CHUNK 4096
#define BIN_BLOCKS ((ETOT + CHUNK - 1) / CHUNK)   // 208

__global__ __launch_bounds__(256) void bin_count_kernel(const int* __restrict__ ei,
                                                        int* __restrict__ histG) {
    __shared__ int histL[NB];
    int t = threadIdx.x;
    for (int b = t; b < NB; b += 256) histL[b] = 0;
    __syncthreads();
    int base = blockIdx.x * CHUNK;
#pragma unroll
    for (int j = 0; j < 16; j++) {
        int e = base + j * 256 + t;
        if (e < ETOT) {
            int d = (e < EDGES) ? ei[EDGES + e] : (e - EDGES);
            atomicAdd(&histL[d >> 7], 1);
        }
    }
    __syncthreads();
    for (int b = t; b < NB; b += 256) {
        int c = histL[b];
        if (c) atomicAdd(&histG[b], c);
    }
}

__global__ __launch_bounds__(512) void bucket_scan_kernel(const int* __restrict__ histG,
                                                          int* __restrict__ bucket_base,
                                                          int* __restrict__ bucket_cursor) {
    __shared__ int sh[512];
    int t = threadIdx.x;
    int v = (t < NB) ? histG[t] : 0;
    sh[t] = v;
    __syncthreads();
    for (int off = 1; off < 512; off <<= 1) {
        int x = sh[t];
        int add = (t >= off) ? sh[t - off] : 0;
        __syncthreads();
        sh[t] = x + add;
        __syncthreads();
    }
    if (t < NB) { int ex = sh[t] - v; bucket_base[t] = ex; bucket_cursor[t] = ex; }
    if (t == 511) bucket_base[NB] = sh[511];
}

__global__ __launch_bounds__(256) void bin_scatter_kernel(const int* __restrict__ ei,
                                                          int* __restrict__ bucket_cursor,
                                                          int2* __restrict__ binned) {
    __shared__ int histL[NB];
    int t = threadIdx.x;
    for (int b = t; b < NB; b += 256) histL[b] = 0;
    __syncthreads();
    int base = blockIdx.x * CHUNK;
#pragma unroll
    for (int j = 0; j < 16; j++) {
        int e = base + j * 256 + t;
        if (e < ETOT) {
            int d = (e < EDGES) ? ei[EDGES + e] : (e - EDGES);
            atomicAdd(&histL[d >> 7], 1);
        }
    }
    __syncthreads();
    for (int b = t; b < NB; b += 256) {
        int c = histL[b];
        histL[b] = c ? atomicAdd(&bucket_cursor[b], c) : 0;
    }
    __syncthreads();
#pragma unroll
    for (int j = 0; j < 16; j++) {
        int e = base + j * 256 + t;
        if (e < ETOT) {
            int s, d;
            if (e < EDGES) { s = ei[e]; d = ei[EDGES + e]; }
            else           { s = d = e - EDGES; }
            int pos = atomicAdd(&histL[d >> 7], 1);
            binned[pos] = make_int2(s, d);
        }
    }
}

__global__ __launch_bounds__(256) void bin_finalize_kernel(const int2* __restrict__ binned,
                                                           const int* __restrict__ bucket_base,
                                                           int* __restrict__ offsets,
                                                           int* __restrict__ csr) {
    __shared__ int histN[128];
    __shared__ int excl[128];
    int b = blockIdx.x, t = threadIdx.x;
    int n0 = b << 7;
    int ebase = bucket_base[b];
    int ecnt  = bucket_base[b + 1] - ebase;
    if (t < 128) histN[t] = 0;
    __syncthreads();
    for (int j = t; j < ecnt; j += 256)
        atomicAdd(&histN[binned[ebase + j].y - n0], 1);
    __syncthreads();
    int v = (t < 128) ? histN[t] : 0;
    if (t < 128) excl[t] = v;
    __syncthreads();
    for (int off = 1; off < 128; off <<= 1) {
        int x = 0, add = 0;
        if (t < 128) { x = excl[t]; if (t >= off) add = excl[t - off]; }
        __syncthreads();
        if (t < 128) excl[t] = x + add;
        __syncthreads();
    }
    if (t < 128) {
        int ex = excl[t] - v;          // exclusive
        int n = n0 + t;
        if (n < N_NODES) offsets[n] = ebase + ex;
        histN[t] = ex;                 // reuse as within-bucket cursor
    }
    if (b == NB - 1 && t == 0) offsets[N_NODES] = ETOT;
    __syncthreads();
    for (int j = t; j < ecnt; j += 256) {
        int2 e = binned[ebase + j];
        int pos = atomicAdd(&histN[e.y - n0], 1);
        csr[ebase + pos] = e.x;
    }
}

// ---------------------------------------------------------------------------
// coef: fold bias+BN into per-channel affine. [A1|B1|A2|B2] (128 each)
// ---------------------------------------------------------------------------
__global__ void coef_kernel(const float* __restrict__ b1, const float* __restrict__ g1,
                            const float* __restrict__ be1, const float* __restrict__ mn1,
                            const float* __restrict__ vr1,
                            const float* __restrict__ b2, const float* __restrict__ g2,
                            const float* __restrict__ be2, const float* __restrict__ mn2,
                            const float* __restrict__ vr2, float* __restrict__ coef) {
    int t = threadIdx.x;
    if (t < 128) {
        float sc = g1[t] * rsqrtf(vr1[t] + 1e-5f);
        coef[t]       = sc;
        coef[128 + t] = be1[t] + (b1[t] - mn1[t]) * sc;
    } else {
        int c = t - 128;
        float sc = g2[c] * rsqrtf(vr2[c] + 1e-5f);
        coef[256 + c] = sc;
        coef[384 + c] = be2[c] + (b2[c] - mn2[c]) * sc;
    }
}

// ---------------------------------------------------------------------------
// W transpose + bf16 convert: Wt[n][k] = bf16(W[k][n])
// ---------------------------------------------------------------------------
__global__ void wtrans_kernel(const float* __restrict__ W1, const float* __restrict__ W2,
                              unsigned short* __restrict__ Wt1, unsigned short* __restrict__ Wt2) {
    int i = blockIdx.x * 256 + threadIdx.x;
    if (i < 256 * 128) { int k = i >> 7, n = i & 127; Wt1[(size_t)n * 256 + k] = f2bf(W1[i]); }
    if (i < 128 * 128) { int k = i >> 7, n = i & 127; Wt2[(size_t)n * 128 + k] = f2bf(W2[i]); }
}

// ---------------------------------------------------------------------------
// MFMA GEMM (bf16 in, fp32 acc) + fused attention dots + bf16 H output.
// ---------------------------------------------------------------------------
#define GR   128
#define KC   64
#define PADK 88
#define PADH 136

union Smem {
    struct { unsigned short Xs[GR][PADK]; unsigned short Ws[HID][PADK]; } s;
    unsigned short Hs[GR][PADH];
};

template<bool XBF16>
__global__ __launch_bounds__(256) void gemm_att_kernel(const void* __restrict__ Xv,
                                                       const unsigned short* __restrict__ Wt,
                                                       const float* __restrict__ att_src,
                                                       const float* __restrict__ att_dst,
                                                       unsigned short* __restrict__ Hout,
                                                       float* __restrict__ aS,
                                                       float* __restrict__ aD, int K) {
    __shared__ Smem sm;
    int t = threadIdx.x, lane = t & 63, w = t >> 6;
    int quad = lane >> 4, nl = lane & 15;
    int rowBase = blockIdx.x * GR;

    floatx4 acc[2][8];
    floatx4 zero = {0.f, 0.f, 0.f, 0.f};
#pragma unroll
    for (int a = 0; a < 2; a++)
#pragma unroll
        for (int b = 0; b < 8; b++) acc[a][b] = zero;

    const float*          Xf = (const float*)Xv;
    const unsigned short* Xb = (const unsigned short*)Xv;

    for (int k0 = 0; k0 < K; k0 += KC) {
#pragma unroll
        for (int it = 0; it < 4; it++) {
            int s5 = t + it * 256;
            int row = s5 >> 3, kg = s5 & 7;
            int gr = rowBase + row;
            unsigned short tmp[8];
            if (XBF16) {
                uint4 v = make_uint4(0, 0, 0, 0);
                if (gr < N_NODES) v = *(const uint4*)&Xb[(size_t)gr * K + k0 + kg * 8];
                *(uint4*)tmp = v;
            } else {
                float4 v0 = make_float4(0, 0, 0, 0), v1 = v0;
                if (gr < N_NODES) {
                    const float* p = &Xf[(size_t)gr * K + k0 + kg * 8];
                    v0 = *(const float4*)p;
                    v1 = *(const float4*)(p + 4);
                }
                tmp[0] = f2bf(v0.x); tmp[1] = f2bf(v0.y); tmp[2] = f2bf(v0.z); tmp[3] = f2bf(v0.w);
                tmp[4] = f2bf(v1.x); tmp[5] = f2bf(v1.y); tmp[6] = f2bf(v1.z); tmp[7] = f2bf(v1.w);
            }
            *(uint4*)&sm.s.Xs[row][kg * 8] = *(uint4*)tmp;
        }
#pragma unroll
        for (int it = 0; it < 4; it++) {
            int s5 = t + it * 256;
            int n = s5 >> 3, kg = s5 & 7;
            *(uint4*)&sm.s.Ws[n][kg * 8] = *(const uint4*)&Wt[(size_t)n * K + k0 + kg * 8];
        }
        __syncthreads();
#pragma unroll
        for (int ks = 0; ks < 2; ks++) {
            int kb = ks * 32 + quad * 8;
            short8 a0 = *(const short8*)&sm.s.Xs[w * 32 + nl][kb];
            short8 a1 = *(const short8*)&sm.s.Xs[w * 32 + 16 + nl][kb];
#pragma unroll
            for (int ct = 0; ct < 8; ct++) {
                short8 b = *(const short8*)&sm.s.Ws[ct * 16 + nl][kb];
                acc[0][ct] = __builtin_amdgcn_mfma_f32_16x16x32_bf16(a0, b, acc[0][ct], 0, 0, 0);
                acc[1][ct] = __builtin_amdgcn_mfma_f32_16x16x32_bf16(a1, b, acc[1][ct], 0, 0, 0);
            }
        }
        __syncthreads();
    }

#pragma unroll
    for (int rt = 0; rt < 2; rt++)
#pragma unroll
        for (int ct = 0; ct < 8; ct++)
#pragma unroll
            for (int r = 0; r < 4; r++)
                sm.Hs[w * 32 + rt * 16 + quad * 4 + r][ct * 16 + nl] = f2bf(acc[rt][ct][r]);

    float asv[8], adv[8];
    {
        const float* ap = &att_src[nl * 8];
        const float* dp = &att_dst[nl * 8];
        *(float4*)&asv[0] = *(const float4*)ap;  *(float4*)&asv[4] = *(const float4*)(ap + 4);
        *(float4*)&adv[0] = *(const float4*)dp;  *(float4*)&adv[4] = *(const float4*)(dp + 4);
    }
    int hd = nl >> 2;
#pragma unroll
    for (int it = 0; it < 8; it++) {
        int rl = w * 32 + it * 4 + quad;
        int grow = rowBase + rl;
        uint4 v = *(const uint4*)&sm.Hs[rl][nl * 8];
        float f[8];
        f[0] = __uint_as_float(v.x << 16); f[1] = __uint_as_float(v.x & 0xffff0000u);
        f[2] = __uint_as_float(v.y << 16); f[3] = __uint_as_float(v.y & 0xffff0000u);
        f[4] = __uint_as_float(v.z << 16); f[5] = __uint_as_float(v.z & 0xffff0000u);
        f[6] = __uint_as_float(v.w << 16); f[7] = __uint_as_float(v.w & 0xffff0000u);
        float ds = 0.f, dd = 0.f;
#pragma unroll
        for (int j = 0; j < 8; j++) {
            ds = fmaf(f[j], asv[j], ds);
            dd = fmaf(f[j], adv[j], dd);
        }
        ds += __shfl_xor(ds, 1); ds += __shfl_xor(ds, 2);
        dd += __shfl_xor(dd, 1); dd += __shfl_xor(dd, 2);
        if (grow < N_NODES) {
            *(uint4*)&Hout[(size_t)grow * HID + nl * 8] = v;
            if ((nl & 3) == 0) { aS[grow * 4 + hd] = ds; aD[grow * 4 + hd] = dd; }
        }
    }
}

// ---------------------------------------------------------------------------
// Fused softmax + aggregate: one wave per node.
// ---------------------------------------------------------------------------
template<bool OUTBF16>
__global__ __launch_bounds__(256) void gather_kernel(const unsigned short* __restrict__ hfeat,
                                                     const float* __restrict__ a_s,
                                                     const float* __restrict__ a_d,
                                                     const int* __restrict__ offsets,
                                                     const int* __restrict__ csr,
                                                     const float* __restrict__ coefA,
                                                     const float* __restrict__ coefB,
                                                     void* __restrict__ outv) {
    __shared__ float alphaS[4][128][4];   // 8 KB
    __shared__ int   srcS[4][128];        // 2 KB
    int t = threadIdx.x, lane = t & 63, ws = t >> 6;
    int n = blockIdx.x * 4 + ws;
    int start = offsets[n], end = offsets[n + 1];
    int deg = end - start;
    float4 ad4 = *(const float4*)&a_d[n * 4];

    int i0 = start + lane, i1 = i0 + 64;
    bool v0 = lane < deg, v1 = lane + 64 < deg;
    int s0 = 0, s1 = 0;
    float e00 = -1e30f, e01 = -1e30f, e02 = -1e30f, e03 = -1e30f;
    float e10 = -1e30f, e11 = -1e30f, e12 = -1e30f, e13 = -1e30f;
    if (v0) {
        s0 = csr[i0];
        float4 as4 = *(const float4*)&a_s[s0 * 4];
        e00 = as4.x + ad4.x; e00 = e00 > 0.f ? e00 : 0.2f * e00;
        e01 = as4.y + ad4.y; e01 = e01 > 0.f ? e01 : 0.2f * e01;
        e02 = as4.z + ad4.z; e02 = e02 > 0.f ? e02 : 0.2f * e02;
        e03 = as4.w + ad4.w; e03 = e03 > 0.f ? e03 : 0.2f * e03;
    }
    if (v1) {
        s1 = csr[i1];
        float4 as4 = *(const float4*)&a_s[s1 * 4];
        e10 = as4.x + ad4.x; e10 = e10 > 0.f ? e10 : 0.2f * e10;
        e11 = as4.y + ad4.y; e11 = e11 > 0.f ? e11 : 0.2f * e11;
        e12 = as4.z + ad4.z; e12 = e12 > 0.f ? e12 : 0.2f * e12;
        e13 = as4.w + ad4.w; e13 = e13 > 0.f ? e13 : 0.2f * e13;
    }
    float m0 = fmaxf(e00, e10), m1 = fmaxf(e01, e11);
    float m2 = fmaxf(e02, e12), m3 = fmaxf(e03, e13);
    for (int i = start + 128 + lane; i < end; i += 64) {
        float4 as4 = *(const float4*)&a_s[csr[i] * 4];
        float f0 = as4.x + ad4.x; f0 = f0 > 0.f ? f0 : 0.2f * f0;
        float f1 = as4.y + ad4.y; f1 = f1 > 0.f ? f1 : 0.2f * f1;
        float f2 = as4.z + ad4.z; f2 = f2 > 0.f ? f2 : 0.2f * f2;
        float f3 = as4.w + ad4.w; f3 = f3 > 0.f ? f3 : 0.2f * f3;
        m0 = fmaxf(m0, f0); m1 = fmaxf(m1, f1);
        m2 = fmaxf(m2, f2); m3 = fmaxf(m3, f3);
    }
#pragma unroll
    for (int off = 32; off > 0; off >>= 1) {
        m0 = fmaxf(m0, __shfl_xor(m0, off));
        m1 = fmaxf(m1, __shfl_xor(m1, off));
        m2 = fmaxf(m2, __shfl_xor(m2, off));
        m3 = fmaxf(m3, __shfl_xor(m3, off));
    }
    float x00 = __expf(e00 - m0), x01 = __expf(e01 - m1);
    float x02 = __expf(e02 - m2), x03 = __expf(e03 - m3);
    float x10 = __expf(e10 - m0), x11 = __expf(e11 - m1);
    float x12 = __expf(e12 - m2), x13 = __expf(e13 - m3);
    float d0 = x00 + x10, d1 = x01 + x11, d2 = x02 + x12, d3 = x03 + x13;
    for (int i = start + 128 + lane; i < end; i += 64) {
        float4 as4 = *(const float4*)&a_s[csr[i] * 4];
        float f0 = as4.x + ad4.x; f0 = f0 > 0.f ? f0 : 0.2f * f0;
        float f1 = as4.y + ad4.y; f1 = f1 > 0.f ? f1 : 0.2f * f1;
        float f2 = as4.z + ad4.z; f2 = f2 > 0.f ? f2 : 0.2f * f2;
        float f3 = as4.w + ad4.w; f3 = f3 > 0.f ? f3 : 0.2f * f3;
        d0 += __expf(f0 - m0); d1 += __expf(f1 - m1);
        d2 += __expf(f2 - m2); d3 += __expf(f3 - m3);
    }
#pragma unroll
    for (int off = 32; off > 0; off >>= 1) {
        d0 += __shfl_xor(d0, off);
        d1 += __shfl_xor(d1, off);
        d2 += __shfl_xor(d2, off);
        d3 += __shfl_xor(d3, off);
    }
    float rd0 = 1.0f / (d0 + 1e-16f);
    float rd1 = 1.0f / (d1 + 1e-16f);
    float rd2 = 1.0f / (d2 + 1e-16f);
    float rd3 = 1.0f / (d3 + 1e-16f);

    if (v0) {
        float4 al; al.x = x00 * rd0; al.y = x01 * rd1; al.z = x02 * rd2; al.w = x03 * rd3;
        *(float4*)&alphaS[ws][lane][0] = al;
        srcS[ws][lane] = s0;
    }
    if (v1) {
        float4 al; al.x = x10 * rd0; al.y = x11 * rd1; al.z = x12 * rd2; al.w = x13 * rd3;
        *(float4*)&alphaS[ws][lane + 64][0] = al;
        srcS[ws][lane + 64] = s1;
    }
    __syncthreads();

    int c = lane * 2;
    int h0 = lane >> 4;
    float mh  = sel4(make_float4(m0, m1, m2, m3), h0);
    float rdh = sel4(make_float4(rd0, rd1, rd2, rd3), h0);
    float adh = sel4(ad4, h0);

    float acc0 = 0.f, acc1 = 0.f;
    int cap = deg < 128 ? deg : 128;
    int j = 0;
    for (; j + 3 < cap; j += 4) {
        int sA = srcS[ws][j], sB = srcS[ws][j + 1], sC = srcS[ws][j + 2], sD = srcS[ws][j + 3];
        float aA = alphaS[ws][j][h0],     aB = alphaS[ws][j + 1][h0];
        float aC = alphaS[ws][j + 2][h0], aD2 = alphaS[ws][j + 3][h0];
        unsigned int vA = *(const unsigned int*)&hfeat[(size_t)sA * HID + c];
        unsigned int vB = *(const unsigned int*)&hfeat[(size_t)sB * HID + c];
        unsigned int vC = *(const unsigned int*)&hfeat[(size_t)sC * HID + c];
        unsigned int vD = *(const unsigned int*)&hfeat[(size_t)sD * HID + c];
        acc0 = fmaf(__uint_as_float(vA << 16),         aA,  acc0);
        acc1 = fmaf(__uint_as_float(vA & 0xffff0000u), aA,  acc1);
        acc0 = fmaf(__uint_as_float(vB << 16),         aB,  acc0);
        acc1 = fmaf(__uint_as_float(vB & 0xffff0000u), aB,  acc1);
        acc0 = fmaf(__uint_as_float(vC << 16),         aC,  acc0);
        acc1 = fmaf(__uint_as_float(vC & 0xffff0000u), aC,  acc1);
        acc0 = fmaf(__uint_as_float(vD << 16),         aD2, acc0);
        acc1 = fmaf(__uint_as_float(vD & 0xffff0000u), aD2, acc1);
    }
    for (; j < cap; j++) {
        int s = srcS[ws][j];
        float al = alphaS[ws][j][h0];
        unsigned int v = *(const unsigned int*)&hfeat[(size_t)s * HID + c];
        acc0 = fmaf(__uint_as_float(v << 16),         al, acc0);
        acc1 = fmaf(__uint_as_float(v & 0xffff0000u), al, acc1);
    }
    for (; j < deg; j++) {
        int s = csr[start + j];
        float as = a_s[s * 4 + h0];
        float e = as + adh; e = e > 0.f ? e : 0.2f * e;
        float al = __expf(e - mh) * rdh;
        unsigned int v = *(const unsigned int*)&hfeat[(size_t)s * HID + c];
        acc0 = fmaf(__uint_as_float(v << 16),         al, acc0);
        acc1 = fmaf(__uint_as_float(v & 0xffff0000u), al, acc1);
    }
    float2 cA = *(const float2*)&coefA[c];
    float2 cB = *(const float2*)&coefB[c];
    float o0 = fmaxf(fmaf(acc0, cA.x, cB.x), 0.f);
    float o1 = fmaxf(fmaf(acc1, cA.y, cB.y), 0.f);
    if (OUTBF16) {
        unsigned int pk = (unsigned int)f2bf(o0) | ((unsigned int)f2bf(o1) << 16);
        ((unsigned int*)outv)[(size_t)n * 64 + lane] = pk;
    } else {
        ((float2*)outv)[(size_t)n * 64 + lane] = make_float2(o0, o1);
    }
}

// ---------------------------------------------------------------------------
extern "C" void kernel_launch(void* const* d_in, const int* in_sizes, int n_in,
                              void* d_out, int out_size, void* d_ws, size_t ws_size,
                              hipStream_t stream) {
    const float* x    = (const float*)d_in[0];
    const int*   ei   = (const int*)d_in[1];
    const float* W1   = (const float*)d_in[2];
    const float* as1  = (const float*)d_in[3];
    const float* ad1  = (const float*)d_in[4];
    const float* b1   = (const float*)d_in[5];
    const float* g1   = (const float*)d_in[6];
    const float* be1  = (const float*)d_in[7];
    const float* mn1  = (const float*)d_in[8];
    const float* vr1  = (const float*)d_in[9];
    const float* W2   = (const float*)d_in[10];
    const float* as2  = (const float*)d_in[11];
    const float* ad2  = (const float*)d_in[12];
    const float* b2   = (const float*)d_in[13];
    const float* g2   = (const float*)d_in[14];
    const float* be2  = (const float*)d_in[15];
    const float* mn2  = (const float*)d_in[16];
    const float* vr2  = (const float*)d_in[17];
    float* out = (float*)d_out;

    unsigned short* hb  = (unsigned short*)d_ws;                  // N*128 bf16
    unsigned short* x2b = hb + (size_t)N_NODES * HID;             // N*128 bf16
    unsigned short* Wt1 = x2b + (size_t)N_NODES * HID;            // 128*256
    unsigned short* Wt2 = Wt1 + 128 * 256;                        // 128*128
    float* aS    = (float*)(Wt2 + 128 * 128);                     // N*4
    float* aD    = aS + N_NODES * NH;                             // N*4
    float* coef  = aD + N_NODES * NH;                             // 512
    int* histG         = (int*)(coef + 512);                      // NB
    int* bucket_base   = histG + NB;                              // NB+1
    int* bucket_cursor = bucket_base + NB + 1;                    // NB
    int* offsets       = bucket_cursor + NB;                      // N+1
    int2* binned       = (int2*)(offsets + N_NODES + 1);          // ETOT int2
    int* csr           = (int*)(binned + ETOT);                   // ETOT

    hipMemsetAsync(histG, 0, NB * sizeof(int), stream);
    bin_count_kernel<<<BIN_BLOCKS, 256, 0, stream>>>(ei, histG);
    bucket_scan_kernel<<<1, 512, 0, stream>>>(histG, bucket_base, bucket_cursor);
    bin_scatter_kernel<<<BIN_BLOCKS, 256, 0, stream>>>(ei, bucket_cursor, binned);
    bin_finalize_kernel<<<NB, 256, 0, stream>>>(binned, bucket_base, offsets, csr);
    coef_kernel<<<1, 256, 0, stream>>>(b1, g1, be1, mn1, vr1, b2, g2, be2, mn2, vr2, coef);
    wtrans_kernel<<<128, 256, 0, stream>>>(W1, W2, Wt1, Wt2);

    int gemmGrid = (N_NODES + GR - 1) / GR;   // 391
    int nodeGrid = N_NODES / 4;               // 12500, exact (4 waves/block)

    // Layer 1
    gemm_att_kernel<false><<<gemmGrid, 256, 0, stream>>>(x, Wt1, as1, ad1, hb, aS, aD, 256);
    gather_kernel<true><<<nodeGrid, 256, 0, stream>>>(hb, aS, aD, offsets, csr,
                                                      coef, coef + 128, (void*)x2b);
    // Layer 2
    gemm_att_kernel<true><<<gemmGrid, 256, 0, stream>>>(x2b, Wt2, as2, ad2, hb, aS, aD, 128);
    gather_kernel<false><<<nodeGrid, 256, 0, stream>>>(hb, aS, aD, offsets, csr,
                                                       coef + 256, coef + 384, (void*)out);
}

// Round 7
// 282.403 us; speedup vs baseline: 2.5192x; 1.0173x over previous
//
#include <hip/hip_runtime.h>
#include <math.h>

#define N_NODES 50000
#define EDGES   800000
#define ETOT    (EDGES + N_NODES)
#define HID     128
#define NH      4

typedef __attribute__((ext_vector_type(8))) short short8;
typedef __attribute__((ext_vector_type(4))) float floatx4;

__device__ inline unsigned short f2bf(float f) {
    unsigned int u = __float_as_uint(f);
    u = u + 0x7FFFu + ((u >> 16) & 1u);   // RNE
    return (unsigned short)(u >> 16);
}

__device__ inline float sel4(float4 v, int h) {
    return h == 0 ? v.x : (h == 1 ? v.y : (h == 2 ? v.z : v.w));
}

// ---------------------------------------------------------------------------
// CSR build via radix binning by dst (line-dense writes)
// ---------------------------------------------------------------------------
#define NB 391
#define CHUNK 4096
#define BIN_BLOCKS ((ETOT + CHUNK - 1) / CHUNK)   // 208

__global__ __launch_bounds__(256) void bin_count_kernel(const int* __restrict__ ei,
                                                        int* __restrict__ histG) {
    __shared__ int histL[NB];
    int t = threadIdx.x;
    for (int b = t; b < NB; b += 256) histL[b] = 0;
    __syncthreads();
    int base = blockIdx.x * CHUNK;
#pragma unroll
    for (int j = 0; j < 16; j++) {
        int e = base + j * 256 + t;
        if (e < ETOT) {
            int d = (e < EDGES) ? ei[EDGES + e] : (e - EDGES);
            atomicAdd(&histL[d >> 7], 1);
        }
    }
    __syncthreads();
    for (int b = t; b < NB; b += 256) {
        int c = histL[b];
        if (c) atomicAdd(&histG[b], c);
    }
}

__global__ __launch_bounds__(512) void bucket_scan_kernel(const int* __restrict__ histG,
                                                          int* __restrict__ bucket_base,
                                                          int* __restrict__ bucket_cursor) {
    __shared__ int sh[512];
    int t = threadIdx.x;
    int v = (t < NB) ? histG[t] : 0;
    sh[t] = v;
    __syncthreads();
    for (int off = 1; off < 512; off <<= 1) {
        int x = sh[t];
        int add = (t >= off) ? sh[t - off] : 0;
        __syncthreads();
        sh[t] = x + add;
        __syncthreads();
    }
    if (t < NB) { int ex = sh[t] - v; bucket_base[t] = ex; bucket_cursor[t] = ex; }
    if (t == 511) bucket_base[NB] = sh[511];
}

__global__ __launch_bounds__(256) void bin_scatter_kernel(const int* __restrict__ ei,
                                                          int* __restrict__ bucket_cursor,
                                                          int2* __restrict__ binned) {
    __shared__ int histL[NB];
    int t = threadIdx.x;
    for (int b = t; b < NB; b += 256) histL[b] = 0;
    __syncthreads();
    int base = blockIdx.x * CHUNK;
#pragma unroll
    for (int j = 0; j < 16; j++) {
        int e = base + j * 256 + t;
        if (e < ETOT) {
            int d = (e < EDGES) ? ei[EDGES + e] : (e - EDGES);
            atomicAdd(&histL[d >> 7], 1);
        }
    }
    __syncthreads();
    for (int b = t; b < NB; b += 256) {
        int c = histL[b];
        histL[b] = c ? atomicAdd(&bucket_cursor[b], c) : 0;
    }
    __syncthreads();
#pragma unroll
    for (int j = 0; j < 16; j++) {
        int e = base + j * 256 + t;
        if (e < ETOT) {
            int s, d;
            if (e < EDGES) { s = ei[e]; d = ei[EDGES + e]; }
            else           { s = d = e - EDGES; }
            int pos = atomicAdd(&histL[d >> 7], 1);
            binned[pos] = make_int2(s, d);
        }
    }
}

__global__ __launch_bounds__(256) void bin_finalize_kernel(const int2* __restrict__ binned,
                                                           const int* __restrict__ bucket_base,
                                                           int* __restrict__ offsets,
                                                           int* __restrict__ csr) {
    __shared__ int histN[128];
    __shared__ int excl[128];
    int b = blockIdx.x, t = threadIdx.x;
    int n0 = b << 7;
    int ebase = bucket_base[b];
    int ecnt  = bucket_base[b + 1] - ebase;
    if (t < 128) histN[t] = 0;
    __syncthreads();
    for (int j = t; j < ecnt; j += 256)
        atomicAdd(&histN[binned[ebase + j].y - n0], 1);
    __syncthreads();
    int v = (t < 128) ? histN[t] : 0;
    if (t < 128) excl[t] = v;
    __syncthreads();
    for (int off = 1; off < 128; off <<= 1) {
        int x = 0, add = 0;
        if (t < 128) { x = excl[t]; if (t >= off) add = excl[t - off]; }
        __syncthreads();
        if (t < 128) excl[t] = x + add;
        __syncthreads();
    }
    if (t < 128) {
        int ex = excl[t] - v;
        int n = n0 + t;
        if (n < N_NODES) offsets[n] = ebase + ex;
        histN[t] = ex;
    }
    if (b == NB - 1 && t == 0) offsets[N_NODES] = ETOT;
    __syncthreads();
    for (int j = t; j < ecnt; j += 256) {
        int2 e = binned[ebase + j];
        int pos = atomicAdd(&histN[e.y - n0], 1);
        csr[ebase + pos] = e.x;
    }
}

// ---------------------------------------------------------------------------
// coef: fold bias+BN into per-channel affine. [A1|B1|A2|B2] (128 each)
// ---------------------------------------------------------------------------
__global__ void coef_kernel(const float* __restrict__ b1, const float* __restrict__ g1,
                            const float* __restrict__ be1, const float* __restrict__ mn1,
                            const float* __restrict__ vr1,
                            const float* __restrict__ b2, const float* __restrict__ g2,
                            const float* __restrict__ be2, const float* __restrict__ mn2,
                            const float* __restrict__ vr2, float* __restrict__ coef) {
    int t = threadIdx.x;
    if (t < 128) {
        float sc = g1[t] * rsqrtf(vr1[t] + 1e-5f);
        coef[t]       = sc;
        coef[128 + t] = be1[t] + (b1[t] - mn1[t]) * sc;
    } else {
        int c = t - 128;
        float sc = g2[c] * rsqrtf(vr2[c] + 1e-5f);
        coef[256 + c] = sc;
        coef[384 + c] = be2[c] + (b2[c] - mn2[c]) * sc;
    }
}

// ---------------------------------------------------------------------------
// W transpose + bf16 convert: Wt[n][k] = bf16(W[k][n])
// ---------------------------------------------------------------------------
__global__ void wtrans_kernel(const float* __restrict__ W1, const float* __restrict__ W2,
                              unsigned short* __restrict__ Wt1, unsigned short* __restrict__ Wt2) {
    int i = blockIdx.x * 256 + threadIdx.x;
    if (i < 256 * 128) { int k = i >> 7, n = i & 127; Wt1[n * 256 + k] = f2bf(W1[i]); }
    if (i < 128 * 128) { int k = i >> 7, n = i & 127; Wt2[n * 128 + k] = f2bf(W2[i]); }
}

// ---------------------------------------------------------------------------
// MFMA GEMM (bf16 in, fp32 acc) + fused attention dots + bf16 H output.
// 32-bit index arithmetic throughout (max index 12.8M).
// ---------------------------------------------------------------------------
#define GR   128
#define KC   64
#define PADK 88
#define PADH 136

union Smem {
    struct { unsigned short Xs[GR][PADK]; unsigned short Ws[HID][PADK]; } s;
    unsigned short Hs[GR][PADH];
};

template<bool XBF16>
__global__ __launch_bounds__(256) void gemm_att_kernel(const void* __restrict__ Xv,
                                                       const unsigned short* __restrict__ Wt,
                                                       const float* __restrict__ att_src,
                                                       const float* __restrict__ att_dst,
                                                       unsigned short* __restrict__ Hout,
                                                       float* __restrict__ aS,
                                                       float* __restrict__ aD, int K) {
    __shared__ Smem sm;
    int t = threadIdx.x, lane = t & 63, w = t >> 6;
    int quad = lane >> 4, nl = lane & 15;
    int rowBase = blockIdx.x * GR;

    floatx4 acc[2][8];
    floatx4 zero = {0.f, 0.f, 0.f, 0.f};
#pragma unroll
    for (int a = 0; a < 2; a++)
#pragma unroll
        for (int b = 0; b < 8; b++) acc[a][b] = zero;

    const float*          Xf = (const float*)Xv;
    const unsigned short* Xb = (const unsigned short*)Xv;

    for (int k0 = 0; k0 < K; k0 += KC) {
#pragma unroll
        for (int it = 0; it < 4; it++) {
            int s5 = t + it * 256;
            int row = s5 >> 3, kg = s5 & 7;
            int gr = rowBase + row;
            unsigned short tmp[8];
            if (XBF16) {
                uint4 v = make_uint4(0, 0, 0, 0);
                if (gr < N_NODES) v = *(const uint4*)&Xb[(unsigned)(gr * K + k0 + kg * 8)];
                *(uint4*)tmp = v;
            } else {
                float4 v0 = make_float4(0, 0, 0, 0), v1 = v0;
                if (gr < N_NODES) {
                    const float* p = &Xf[(unsigned)(gr * K + k0 + kg * 8)];
                    v0 = *(const float4*)p;
                    v1 = *(const float4*)(p + 4);
                }
                tmp[0] = f2bf(v0.x); tmp[1] = f2bf(v0.y); tmp[2] = f2bf(v0.z); tmp[3] = f2bf(v0.w);
                tmp[4] = f2bf(v1.x); tmp[5] = f2bf(v1.y); tmp[6] = f2bf(v1.z); tmp[7] = f2bf(v1.w);
            }
            *(uint4*)&sm.s.Xs[row][kg * 8] = *(uint4*)tmp;
        }
#pragma unroll
        for (int it = 0; it < 4; it++) {
            int s5 = t + it * 256;
            int n = s5 >> 3, kg = s5 & 7;
            *(uint4*)&sm.s.Ws[n][kg * 8] = *(const uint4*)&Wt[(unsigned)(n * K + k0 + kg * 8)];
        }
        __syncthreads();
#pragma unroll
        for (int ks = 0; ks < 2; ks++) {
            int kb = ks * 32 + quad * 8;
            short8 a0 = *(const short8*)&sm.s.Xs[w * 32 + nl][kb];
            short8 a1 = *(const short8*)&sm.s.Xs[w * 32 + 16 + nl][kb];
#pragma unroll
            for (int ct = 0; ct < 8; ct++) {
                short8 b = *(const short8*)&sm.s.Ws[ct * 16 + nl][kb];
                acc[0][ct] = __builtin_amdgcn_mfma_f32_16x16x32_bf16(a0, b, acc[0][ct], 0, 0, 0);
                acc[1][ct] = __builtin_amdgcn_mfma_f32_16x16x32_bf16(a1, b, acc[1][ct], 0, 0, 0);
            }
        }
        __syncthreads();
    }

#pragma unroll
    for (int rt = 0; rt < 2; rt++)
#pragma unroll
        for (int ct = 0; ct < 8; ct++)
#pragma unroll
            for (int r = 0; r < 4; r++)
                sm.Hs[w * 32 + rt * 16 + quad * 4 + r][ct * 16 + nl] = f2bf(acc[rt][ct][r]);

    float asv[8], adv[8];
    {
        const float* ap = &att_src[nl * 8];
        const float* dp = &att_dst[nl * 8];
        *(float4*)&asv[0] = *(const float4*)ap;  *(float4*)&asv[4] = *(const float4*)(ap + 4);
        *(float4*)&adv[0] = *(const float4*)dp;  *(float4*)&adv[4] = *(const float4*)(dp + 4);
    }
    int hd = nl >> 2;
#pragma unroll
    for (int it = 0; it < 8; it++) {
        int rl = w * 32 + it * 4 + quad;
        int grow = rowBase + rl;
        uint4 v = *(const uint4*)&sm.Hs[rl][nl * 8];
        float f[8];
        f[0] = __uint_as_float(v.x << 16); f[1] = __uint_as_float(v.x & 0xffff0000u);
        f[2] = __uint_as_float(v.y << 16); f[3] = __uint_as_float(v.y & 0xffff0000u);
        f[4] = __uint_as_float(v.z << 16); f[5] = __uint_as_float(v.z & 0xffff0000u);
        f[6] = __uint_as_float(v.w << 16); f[7] = __uint_as_float(v.w & 0xffff0000u);
        float ds = 0.f, dd = 0.f;
#pragma unroll
        for (int j = 0; j < 8; j++) {
            ds = fmaf(f[j], asv[j], ds);
            dd = fmaf(f[j], adv[j], dd);
        }
        ds += __shfl_xor(ds, 1); ds += __shfl_xor(ds, 2);
        dd += __shfl_xor(dd, 1); dd += __shfl_xor(dd, 2);
        if (grow < N_NODES) {
            *(uint4*)&Hout[(unsigned)(grow * HID + nl * 8)] = v;
            if ((nl & 3) == 0) { aS[grow * 4 + hd] = ds; aD[grow * 4 + hd] = dd; }
        }
    }
}

// ---------------------------------------------------------------------------
// Fused softmax + aggregate: one wave per node.
// Phase A: softmax; stores pre-shifted byte offsets (s<<8) and head-transposed
// alpha (alphaT[h][j], stride 132 to spread banks).
// Phase B: per edge = 2 broadcast ds_reads + v_add + global_load_dword
// (32-bit voffset) + 2 unpack + 2 fma. All index math 32-bit.
// ---------------------------------------------------------------------------
#define ASTRIDE 132

template<bool OUTBF16>
__global__ __launch_bounds__(256) void gather_kernel(const unsigned short* __restrict__ hfeat,
                                                     const float* __restrict__ a_s,
                                                     const float* __restrict__ a_d,
                                                     const int* __restrict__ offsets,
                                                     const int* __restrict__ csr,
                                                     const float* __restrict__ coefA,
                                                     const float* __restrict__ coefB,
                                                     void* __restrict__ outv) {
    __shared__ float alphaT[4][4][ASTRIDE];   // 8448 B
    __shared__ int   offS[4][128];            // 2048 B
    int t = threadIdx.x, lane = t & 63, ws = t >> 6;
    int n = blockIdx.x * 4 + ws;
    int start = offsets[n], end = offsets[n + 1];
    int deg = end - start;
    float4 ad4 = *(const float4*)&a_d[(unsigned)(n * 4)];

    int i0 = start + lane, i1 = i0 + 64;
    bool v0 = lane < deg, v1 = lane + 64 < deg;
    int s0 = 0, s1 = 0;
    float e00 = -1e30f, e01 = -1e30f, e02 = -1e30f, e03 = -1e30f;
    float e10 = -1e30f, e11 = -1e30f, e12 = -1e30f, e13 = -1e30f;
    if (v0) {
        s0 = csr[i0];
        float4 as4 = *(const float4*)&a_s[(unsigned)(s0 * 4)];
        e00 = as4.x + ad4.x; e00 = e00 > 0.f ? e00 : 0.2f * e00;
        e01 = as4.y + ad4.y; e01 = e01 > 0.f ? e01 : 0.2f * e01;
        e02 = as4.z + ad4.z; e02 = e02 > 0.f ? e02 : 0.2f * e02;
        e03 = as4.w + ad4.w; e03 = e03 > 0.f ? e03 : 0.2f * e03;
    }
    if (v1) {
        s1 = csr[i1];
        float4 as4 = *(const float4*)&a_s[(unsigned)(s1 * 4)];
        e10 = as4.x + ad4.x; e10 = e10 > 0.f ? e10 : 0.2f * e10;
        e11 = as4.y + ad4.y; e11 = e11 > 0.f ? e11 : 0.2f * e11;
        e12 = as4.z + ad4.z; e12 = e12 > 0.f ? e12 : 0.2f * e12;
        e13 = as4.w + ad4.w; e13 = e13 > 0.f ? e13 : 0.2f * e13;
    }
    float m0 = fmaxf(e00, e10), m1 = fmaxf(e01, e11);
    float m2 = fmaxf(e02, e12), m3 = fmaxf(e03, e13);
    for (int i = start + 128 + lane; i < end; i += 64) {
        float4 as4 = *(const float4*)&a_s[(unsigned)(csr[i] * 4)];
        float f0 = as4.x + ad4.x; f0 = f0 > 0.f ? f0 : 0.2f * f0;
        float f1 = as4.y + ad4.y; f1 = f1 > 0.f ? f1 : 0.2f * f1;
        float f2 = as4.z + ad4.z; f2 = f2 > 0.f ? f2 : 0.2f * f2;
        float f3 = as4.w + ad4.w; f3 = f3 > 0.f ? f3 : 0.2f * f3;
        m0 = fmaxf(m0, f0); m1 = fmaxf(m1, f1);
        m2 = fmaxf(m2, f2); m3 = fmaxf(m3, f3);
    }
#pragma unroll
    for (int off = 32; off > 0; off >>= 1) {
        m0 = fmaxf(m0, __shfl_xor(m0, off));
        m1 = fmaxf(m1, __shfl_xor(m1, off));
        m2 = fmaxf(m2, __shfl_xor(m2, off));
        m3 = fmaxf(m3, __shfl_xor(m3, off));
    }
    float x00 = __expf(e00 - m0), x01 = __expf(e01 - m1);
    float x02 = __expf(e02 - m2), x03 = __expf(e03 - m3);
    float x10 = __expf(e10 - m0), x11 = __expf(e11 - m1);
    float x12 = __expf(e12 - m2), x13 = __expf(e13 - m3);
    float d0 = x00 + x10, d1 = x01 + x11, d2 = x02 + x12, d3 = x03 + x13;
    for (int i = start + 128 + lane; i < end; i += 64) {
        float4 as4 = *(const float4*)&a_s[(unsigned)(csr[i] * 4)];
        float f0 = as4.x + ad4.x; f0 = f0 > 0.f ? f0 : 0.2f * f0;
        float f1 = as4.y + ad4.y; f1 = f1 > 0.f ? f1 : 0.2f * f1;
        float f2 = as4.z + ad4.z; f2 = f2 > 0.f ? f2 : 0.2f * f2;
        float f3 = as4.w + ad4.w; f3 = f3 > 0.f ? f3 : 0.2f * f3;
        d0 += __expf(f0 - m0); d1 += __expf(f1 - m1);
        d2 += __expf(f2 - m2); d3 += __expf(f3 - m3);
    }
#pragma unroll
    for (int off = 32; off > 0; off >>= 1) {
        d0 += __shfl_xor(d0, off);
        d1 += __shfl_xor(d1, off);
        d2 += __shfl_xor(d2, off);
        d3 += __shfl_xor(d3, off);
    }
    float rd0 = 1.0f / (d0 + 1e-16f);
    float rd1 = 1.0f / (d1 + 1e-16f);
    float rd2 = 1.0f / (d2 + 1e-16f);
    float rd3 = 1.0f / (d3 + 1e-16f);

    if (v0) {
        alphaT[ws][0][lane] = x00 * rd0;
        alphaT[ws][1][lane] = x01 * rd1;
        alphaT[ws][2][lane] = x02 * rd2;
        alphaT[ws][3][lane] = x03 * rd3;
        offS[ws][lane] = s0 << 8;          // byte offset of h row (128*2B)
    }
    if (v1) {
        alphaT[ws][0][lane + 64] = x10 * rd0;
        alphaT[ws][1][lane + 64] = x11 * rd1;
        alphaT[ws][2][lane + 64] = x12 * rd2;
        alphaT[ws][3][lane + 64] = x13 * rd3;
        offS[ws][lane + 64] = s1 << 8;
    }
    __syncthreads();

    int c = lane * 2;
    int h0 = lane >> 4;
    int lane4 = lane * 4;                   // byte offset of channel pair
    const char* hbase = (const char*)hfeat;
    float mh  = sel4(make_float4(m0, m1, m2, m3), h0);
    float rdh = sel4(make_float4(rd0, rd1, rd2, rd3), h0);
    float adh = sel4(ad4, h0);

    float acc0 = 0.f, acc1 = 0.f;
    int cap = deg < 128 ? deg : 128;
    int j = 0;
    for (; j + 3 < cap; j += 4) {
        unsigned oA = (unsigned)(offS[ws][j]     + lane4);
        unsigned oB = (unsigned)(offS[ws][j + 1] + lane4);
        unsigned oC = (unsigned)(offS[ws][j + 2] + lane4);
        unsigned oD = (unsigned)(offS[ws][j + 3] + lane4);
        float aA = alphaT[ws][h0][j],     aB = alphaT[ws][h0][j + 1];
        float aC = alphaT[ws][h0][j + 2], aD2 = alphaT[ws][h0][j + 3];
        unsigned int vA = *(const unsigned int*)(hbase + oA);
        unsigned int vB = *(const unsigned int*)(hbase + oB);
        unsigned int vC = *(const unsigned int*)(hbase + oC);
        unsigned int vD = *(const unsigned int*)(hbase + oD);
        acc0 = fmaf(__uint_as_float(vA << 16),         aA,  acc0);
        acc1 = fmaf(__uint_as_float(vA & 0xffff0000u), aA,  acc1);
        acc0 = fmaf(__uint_as_float(vB << 16),         aB,  acc0);
        acc1 = fmaf(__uint_as_float(vB & 0xffff0000u), aB,  acc1);
        acc0 = fmaf(__uint_as_float(vC << 16),         aC,  acc0);
        acc1 = fmaf(__uint_as_float(vC & 0xffff0000u), aC,  acc1);
        acc0 = fmaf(__uint_as_float(vD << 16),         aD2, acc0);
        acc1 = fmaf(__uint_as_float(vD & 0xffff0000u), aD2, acc1);
    }
    for (; j < cap; j++) {
        unsigned o = (unsigned)(offS[ws][j] + lane4);
        float al = alphaT[ws][h0][j];
        unsigned int v = *(const unsigned int*)(hbase + o);
        acc0 = fmaf(__uint_as_float(v << 16),         al, acc0);
        acc1 = fmaf(__uint_as_float(v & 0xffff0000u), al, acc1);
    }
    for (; j < deg; j++) {   // rare deg>128 tail: recompute alpha
        int s = csr[start + j];
        float as = a_s[(unsigned)(s * 4 + h0)];
        float e = as + adh; e = e > 0.f ? e : 0.2f * e;
        float al = __expf(e - mh) * rdh;
        unsigned int v = *(const unsigned int*)(hbase + (unsigned)((s << 8) + lane4));
        acc0 = fmaf(__uint_as_float(v << 16),         al, acc0);
        acc1 = fmaf(__uint_as_float(v & 0xffff0000u), al, acc1);
    }
    float2 cA = *(const float2*)&coefA[c];
    float2 cB = *(const float2*)&coefB[c];
    float o0 = fmaxf(fmaf(acc0, cA.x, cB.x), 0.f);
    float o1 = fmaxf(fmaf(acc1, cA.y, cB.y), 0.f);
    if (OUTBF16) {
        unsigned int pk = (unsigned int)f2bf(o0) | ((unsigned int)f2bf(o1) << 16);
        ((unsigned int*)outv)[(unsigned)(n * 64 + lane)] = pk;
    } else {
        ((float2*)outv)[(unsigned)(n * 64 + lane)] = make_float2(o0, o1);
    }
}

// ---------------------------------------------------------------------------
extern "C" void kernel_launch(void* const* d_in, const int* in_sizes, int n_in,
                              void* d_out, int out_size, void* d_ws, size_t ws_size,
                              hipStream_t stream) {
    const float* x    = (const float*)d_in[0];
    const int*   ei   = (const int*)d_in[1];
    const float* W1   = (const float*)d_in[2];
    const float* as1  = (const float*)d_in[3];
    const float* ad1  = (const float*)d_in[4];
    const float* b1   = (const float*)d_in[5];
    const float* g1   = (const float*)d_in[6];
    const float* be1  = (const float*)d_in[7];
    const float* mn1  = (const float*)d_in[8];
    const float* vr1  = (const float*)d_in[9];
    const float* W2   = (const float*)d_in[10];
    const float* as2  = (const float*)d_in[11];
    const float* ad2  = (const float*)d_in[12];
    const float* b2   = (const float*)d_in[13];
    const float* g2   = (const float*)d_in[14];
    const float* be2  = (const float*)d_in[15];
    const float* mn2  = (const float*)d_in[16];
    const float* vr2  = (const float*)d_in[17];
    float* out = (float*)d_out;

    unsigned short* hb  = (unsigned short*)d_ws;                  // N*128 bf16
    unsigned short* x2b = hb + (size_t)N_NODES * HID;             // N*128 bf16
    unsigned short* Wt1 = x2b + (size_t)N_NODES * HID;            // 128*256
    unsigned short* Wt2 = Wt1 + 128 * 256;                        // 128*128
    float* aS    = (float*)(Wt2 + 128 * 128);                     // N*4
    float* aD    = aS + N_NODES * NH;                             // N*4
    float* coef  = aD + N_NODES * NH;                             // 512
    int* histG         = (int*)(coef + 512);                      // NB
    int* bucket_base   = histG + NB;                              // NB+1
    int* bucket_cursor = bucket_base + NB + 1;                    // NB
    int* offsets       = bucket_cursor + NB;                      // N+1
    int2* binned       = (int2*)(offsets + N_NODES + 1);          // ETOT int2
    int* csr           = (int*)(binned + ETOT);                   // ETOT

    hipMemsetAsync(histG, 0, NB * sizeof(int), stream);
    bin_count_kernel<<<BIN_BLOCKS, 256, 0, stream>>>(ei, histG);
    bucket_scan_kernel<<<1, 512, 0, stream>>>(histG, bucket_base, bucket_cursor);
    bin_scatter_kernel<<<BIN_BLOCKS, 256, 0, stream>>>(ei, bucket_cursor, binned);
    bin_finalize_kernel<<<NB, 256, 0, stream>>>(binned, bucket_base, offsets, csr);
    coef_kernel<<<1, 256, 0, stream>>>(b1, g1, be1, mn1, vr1, b2, g2, be2, mn2, vr2, coef);
    wtrans_kernel<<<128, 256, 0, stream>>>(W1, W2, Wt1, Wt2);

    int gemmGrid = (N_NODES + GR - 1) / GR;   // 391
    int nodeGrid = N_NODES / 4;               // 12500, exact (4 waves/block)

    // Layer 1
    gemm_att_kernel<false><<<gemmGrid, 256, 0, stream>>>(x, Wt1, as1, ad1, hb, aS, aD, 256);
    gather_kernel<true><<<nodeGrid, 256, 0, stream>>>(hb, aS, aD, offsets, csr,
                                                      coef, coef + 128, (void*)x2b);
    // Layer 2
    gemm_att_kernel<true><<<gemmGrid, 256, 0, stream>>>(x2b, Wt2, as2, ad2, hb, aS, aD, 128);
    gather_kernel<false><<<nodeGrid, 256, 0, stream>>>(hb, aS, aD, offsets, csr,
                                                       coef + 256, coef + 384, (void*)out);
}